// Round 1
// 629.013 us; speedup vs baseline: 1.0418x; 1.0418x over previous
//
#include <hip/hip_runtime.h>

#define BLK 256

// broadcast lane l of v across the wave (l wave-uniform; dynamic is legal)
__device__ __forceinline__ float bcast(float v, int l) {
    return __int_as_float(__builtin_amdgcn_readlane(__float_as_int(v), l));
}
// fp32 <-> bf16 (round-to-nearest-even)
__device__ __forceinline__ unsigned short f2bf(float f) {
    unsigned u = __float_as_uint(f);
    return (unsigned short)((u + 0x7FFFu + ((u >> 16) & 1u)) >> 16);
}
__device__ __forceinline__ float bf2f(unsigned short b) {
    return __uint_as_float(((unsigned)b) << 16);
}
// physical XCD (chiplet) id of this wave's CU [measured: learn_hip m09]
__device__ __forceinline__ int xcc_id() {
    int x;
    asm volatile("s_getreg_b32 %0, hwreg(HW_REG_XCC_ID)" : "=s"(x));
    return x & 7;
}
// XCD-local atomic: workgroup scope drops sc1 -> RMW executes in the local TCC
// (shared by all CUs on this XCD). Correct because each XCD only touches its
// own private counter copy.
__device__ __forceinline__ int atadd_xcd(int* p) {
    return __hip_atomic_fetch_add(p, 1, __ATOMIC_RELAXED, __HIP_MEMORY_SCOPE_WORKGROUP);
}

// ================= batched CSR skeleton (all 4 graphs) =================
// hist counts into 8 XCD-private histogram copies with XCD-local atomics
// (device-scope atomics were ~33B of fabric RMW each -> 115MB WRITE_SIZE,
// 150us). rank = (xcd<<13) | rank-within-xcd; fill then needs NO atomics:
// slot = base8[xcd][dst] + rank.

__global__ void k_hist_all(const int* __restrict__ dv, const int* __restrict__ dh,
                           const int* __restrict__ di, const int* __restrict__ ds,
                           int* __restrict__ c8v, int* __restrict__ c8h,
                           int* __restrict__ c8i, int* __restrict__ c8s,
                           unsigned short* __restrict__ rkv, unsigned short* __restrict__ rkh,
                           unsigned short* __restrict__ rki, unsigned short* __restrict__ rks,
                           int Ev, int Eh, int Ei, int Es, int nv, int ns) {
    int xcd = xcc_id();
    int e = blockIdx.x * blockDim.x + threadIdx.x;
    if (e < Ev) {
        int r = atadd_xcd(&c8v[(size_t)xcd * nv + dv[e]]);
        rkv[e] = (unsigned short)((xcd << 13) | r);
        return;
    }
    e -= Ev;
    if (e < Eh) {
        int r = atadd_xcd(&c8h[(size_t)xcd * ns + dh[e]]);
        rkh[e] = (unsigned short)((xcd << 13) | r);
        return;
    }
    e -= Eh;
    if (e < Ei) {
        int r = atadd_xcd(&c8i[(size_t)xcd * ns + di[e]]);
        rki[e] = (unsigned short)((xcd << 13) | r);
        return;
    }
    e -= Ei;
    if (e < Es) {
        int r = atadd_xcd(&c8s[(size_t)xcd * ns + ds[e]]);
        rks[e] = (unsigned short)((xcd << 13) | r);
    }
}

// batched per-256-block exclusive scan over deg = sum of 8 XCD copies;
// also emits dinv=rsqrt(deg) for vv/ss
__global__ void k_scanb_all(const int* __restrict__ c8v, const int* __restrict__ c8h,
                            const int* __restrict__ c8i, const int* __restrict__ c8s,
                            int* __restrict__ rv, int* __restrict__ rh,
                            int* __restrict__ ri, int* __restrict__ rs,
                            float* __restrict__ dv, float* __restrict__ ds,
                            int* __restrict__ bsum, int nv, int ns, int nbv, int nbs) {
    __shared__ int sh[256];
    int blk = blockIdx.x;
    const int* c8; int* rp; float* dinv; int n; int lb;
    if (blk < nbv)                { c8 = c8v; rp = rv; dinv = dv;      n = nv; lb = blk; }
    else if (blk < nbv + nbs)     { c8 = c8h; rp = rh; dinv = nullptr; n = ns; lb = blk - nbv; }
    else if (blk < nbv + 2 * nbs) { c8 = c8i; rp = ri; dinv = nullptr; n = ns; lb = blk - nbv - nbs; }
    else                          { c8 = c8s; rp = rs; dinv = ds;      n = ns; lb = blk - nbv - 2 * nbs; }
    int i = lb * 256 + threadIdx.x;
    int v = 0;
    if (i < n) {
        #pragma unroll
        for (int k = 0; k < 8; k++) v += c8[(size_t)k * n + i];
    }
    if (dinv && i < n) dinv[i] = v > 0 ? rsqrtf((float)v) : 0.f;
    sh[threadIdx.x] = v; __syncthreads();
    for (int off = 1; off < 256; off <<= 1) {
        int t = (threadIdx.x >= off) ? sh[threadIdx.x - off] : 0;
        __syncthreads();
        sh[threadIdx.x] += t; __syncthreads();
    }
    if (i < n) rp[i] = sh[threadIdx.x] - v;
    if (threadIdx.x == 255) bsum[blk] = sh[255];
}

__global__ void k_scant_all(int* __restrict__ bsum, int nbv, int nbs) {
    __shared__ int sh[1024];
    int g = blockIdx.x;
    int off = (g == 0) ? 0 : nbv + (g - 1) * nbs;
    int nb  = (g == 0) ? nbv : nbs;
    int tid = threadIdx.x;
    int v = (tid < nb) ? bsum[off + tid] : 0;
    sh[tid] = v; __syncthreads();
    for (int o2 = 1; o2 < 1024; o2 <<= 1) {
        int t = (tid >= o2) ? sh[tid - o2] : 0;
        __syncthreads();
        sh[tid] += t; __syncthreads();
    }
    if (tid < nb) bsum[off + tid] = sh[tid] - v;
}

// finalize rowptr and emit per-XCD fill bases:
// base8[k][i] = rowptr[i] + sum_{k'<k} cnt8[k'][i]
__global__ void k_scana_all(int* __restrict__ rv, int* __restrict__ rh,
                            int* __restrict__ ri, int* __restrict__ rs,
                            const int* __restrict__ c8v, const int* __restrict__ c8h,
                            const int* __restrict__ c8i, const int* __restrict__ c8s,
                            int* __restrict__ bv8, int* __restrict__ bh8,
                            int* __restrict__ bi8, int* __restrict__ bs8,
                            const int* __restrict__ bsum, int nv, int ns, int nbv, int nbs,
                            int Ev, int Eh, int Ei, int Es) {
    int blk = blockIdx.x;
    int* rp; const int* c8; int* b8; int n; int lb; int E;
    if (blk < nbv)                { rp = rv; c8 = c8v; b8 = bv8; n = nv; lb = blk;               E = Ev; }
    else if (blk < nbv + nbs)     { rp = rh; c8 = c8h; b8 = bh8; n = ns; lb = blk - nbv;         E = Eh; }
    else if (blk < nbv + 2 * nbs) { rp = ri; c8 = c8i; b8 = bi8; n = ns; lb = blk - nbv - nbs;   E = Ei; }
    else                          { rp = rs; c8 = c8s; b8 = bs8; n = ns; lb = blk - nbv - 2*nbs; E = Es; }
    int i = lb * 256 + threadIdx.x;
    if (i < n) {
        int base = rp[i] + bsum[blk];
        rp[i] = base;
        #pragma unroll
        for (int k = 0; k < 8; k++) {
            b8[(size_t)k * n + i] = base;
            base += c8[(size_t)k * n + i];
        }
    }
    if (i == 0) rp[n] = E;
}

// one dispatch: atomic-free fill of all 4 CSRs
__global__ void k_fill_all(
    const int* __restrict__ vv_s, const int* __restrict__ vv_d,
    const unsigned short* __restrict__ rkv, const int* __restrict__ bv8, int* __restrict__ vvsrc,
    const int* __restrict__ h_s, const int* __restrict__ h_d, const float* __restrict__ hw,
    const unsigned short* __restrict__ rkh, const int* __restrict__ bh8, int2* __restrict__ hsw,
    const int* __restrict__ in_s, const int* __restrict__ in_d,
    const unsigned short* __restrict__ rki, const int* __restrict__ bi8, int* __restrict__ insrc,
    const int* __restrict__ ss_s, const int* __restrict__ ss_d,
    const unsigned short* __restrict__ rks, const int* __restrict__ bs8, int* __restrict__ sssrc,
    int Ev, int Eh, int Ei, int Es, int nv, int ns) {
    int e = blockIdx.x * blockDim.x + threadIdx.x;
    if (e < Ev) {
        unsigned rk = rkv[e];
        vvsrc[bv8[(size_t)(rk >> 13) * nv + vv_d[e]] + (rk & 0x1FFFu)] = vv_s[e];
        return;
    }
    e -= Ev;
    if (e < Eh) {
        unsigned rk = rkh[e];
        hsw[bh8[(size_t)(rk >> 13) * ns + h_d[e]] + (rk & 0x1FFFu)] =
            make_int2(h_s[e], __float_as_int(hw[e]));
        return;
    }
    e -= Eh;
    if (e < Ei) {
        unsigned rk = rki[e];
        insrc[bi8[(size_t)(rk >> 13) * ns + in_d[e]] + (rk & 0x1FFFu)] = in_s[e];
        return;
    }
    e -= Ei;
    if (e < Es) {
        unsigned rk = rks[e];
        sssrc[bs8[(size_t)(rk >> 13) * ns + ss_d[e]] + (rk & 0x1FFFu)] = ss_s[e];
    }
}

// ================= gathers =================

__global__ void k_gather5(const float* __restrict__ x, const int* __restrict__ rowptr,
                          const int* __restrict__ csr_src, const float* __restrict__ dinv,
                          float* __restrict__ out, int n) {
    int d = blockIdx.x * blockDim.x + threadIdx.x;
    if (d >= n) return;
    int b = rowptr[d], e = rowptr[d + 1];
    float dd = dinv[d];
    float a0 = 0, a1 = 0, a2 = 0, a3 = 0, a4 = 0;
    int p = b;
    for (; p + 4 <= e; p += 4) {
        int s0 = csr_src[p], s1 = csr_src[p+1], s2 = csr_src[p+2], s3 = csr_src[p+3];
        const float* x0 = x + (size_t)s0 * 5;
        const float* x1 = x + (size_t)s1 * 5;
        const float* x2 = x + (size_t)s2 * 5;
        const float* x3 = x + (size_t)s3 * 5;
        float w0 = dd * dinv[s0], w1 = dd * dinv[s1], w2 = dd * dinv[s2], w3 = dd * dinv[s3];
        a0 += x0[0]*w0 + x1[0]*w1 + x2[0]*w2 + x3[0]*w3;
        a1 += x0[1]*w0 + x1[1]*w1 + x2[1]*w2 + x3[1]*w3;
        a2 += x0[2]*w0 + x1[2]*w1 + x2[2]*w2 + x3[2]*w3;
        a3 += x0[3]*w0 + x1[3]*w1 + x2[3]*w2 + x3[3]*w3;
        a4 += x0[4]*w0 + x1[4]*w1 + x2[4]*w2 + x3[4]*w3;
    }
    for (; p < e; p++) {
        int s = csr_src[p];
        float w = dd * dinv[s];
        const float* xp = x + (size_t)s * 5;
        a0 += xp[0]*w; a1 += xp[1]*w; a2 += xp[2]*w; a3 += xp[3]*w; a4 += xp[4]*w;
    }
    float* op = out + (size_t)d * 5;
    op[0] = a0; op[1] = a1; op[2] = a2; op[3] = a3; op[4] = a4;
}

// 64-ch gather over bf16 rows: wave per dst row; 4 groups x 16 lanes x ushort4(8B);
// 4-edge-deep MLP; fp32 accumulate.
// MODE: 0 = plain sum, 1 = per-edge weight (int2 packed), 2 = symmetric gcn norm
// OUTBF: write bf16 row (for next gather hop) vs fp32 row
template<int MODE, bool OUTBF>
__global__ void k_gather64(const unsigned short* __restrict__ xbf, const int* __restrict__ rowptr,
                           const int* __restrict__ csr_src, const int2* __restrict__ csr_sw,
                           const float* __restrict__ dinv, void* __restrict__ outp, int n) {
    int wid = (int)(((long long)blockIdx.x * blockDim.x + threadIdx.x) >> 6);
    if (wid >= n) return;
    int lane = threadIdx.x & 63;
    int g = lane >> 4, q = lane & 15;
    int b = rowptr[wid], e = rowptr[wid + 1];
    float dd = (MODE == 2) ? dinv[wid] : 0.f;
    float4 acc = make_float4(0.f, 0.f, 0.f, 0.f);
    int p = b + g;
    for (; p + 12 < e; p += 16) {
        int s0, s1, s2, s3;
        float w0 = 1.f, w1 = 1.f, w2 = 1.f, w3 = 1.f;
        if (MODE == 1) {
            int2 e0 = csr_sw[p], e1 = csr_sw[p+4], e2 = csr_sw[p+8], e3 = csr_sw[p+12];
            s0 = e0.x; w0 = __int_as_float(e0.y);
            s1 = e1.x; w1 = __int_as_float(e1.y);
            s2 = e2.x; w2 = __int_as_float(e2.y);
            s3 = e3.x; w3 = __int_as_float(e3.y);
        } else {
            s0 = csr_src[p]; s1 = csr_src[p+4]; s2 = csr_src[p+8]; s3 = csr_src[p+12];
            if (MODE == 2) {
                w0 = dd * dinv[s0]; w1 = dd * dinv[s1];
                w2 = dd * dinv[s2]; w3 = dd * dinv[s3];
            }
        }
        ushort4 u0 = ((const ushort4*)(xbf + (size_t)s0 * 64))[q];
        ushort4 u1 = ((const ushort4*)(xbf + (size_t)s1 * 64))[q];
        ushort4 u2 = ((const ushort4*)(xbf + (size_t)s2 * 64))[q];
        ushort4 u3 = ((const ushort4*)(xbf + (size_t)s3 * 64))[q];
        acc.x += bf2f(u0.x)*w0 + bf2f(u1.x)*w1 + bf2f(u2.x)*w2 + bf2f(u3.x)*w3;
        acc.y += bf2f(u0.y)*w0 + bf2f(u1.y)*w1 + bf2f(u2.y)*w2 + bf2f(u3.y)*w3;
        acc.z += bf2f(u0.z)*w0 + bf2f(u1.z)*w1 + bf2f(u2.z)*w2 + bf2f(u3.z)*w3;
        acc.w += bf2f(u0.w)*w0 + bf2f(u1.w)*w1 + bf2f(u2.w)*w2 + bf2f(u3.w)*w3;
    }
    for (; p < e; p += 4) {
        int s; float w = 1.f;
        if (MODE == 1) { int2 e0 = csr_sw[p]; s = e0.x; w = __int_as_float(e0.y); }
        else { s = csr_src[p]; if (MODE == 2) w = dd * dinv[s]; }
        ushort4 u = ((const ushort4*)(xbf + (size_t)s * 64))[q];
        acc.x += bf2f(u.x)*w; acc.y += bf2f(u.y)*w;
        acc.z += bf2f(u.z)*w; acc.w += bf2f(u.w)*w;
    }
    #pragma unroll
    for (int off = 16; off < 64; off <<= 1) {
        acc.x += __shfl_xor(acc.x, off, 64);
        acc.y += __shfl_xor(acc.y, off, 64);
        acc.z += __shfl_xor(acc.z, off, 64);
        acc.w += __shfl_xor(acc.w, off, 64);
    }
    if (g == 0) {
        if (OUTBF) {
            ushort4 ov;
            ov.x = f2bf(acc.x); ov.y = f2bf(acc.y); ov.z = f2bf(acc.z); ov.w = f2bf(acc.w);
            ((ushort4*)outp)[(size_t)wid * 16 + q] = ov;
        } else {
            ((float4*)outp)[(size_t)wid * 16 + q] = acc;
        }
    }
}

// ================= dense combines (wave-tiled register GEMMs) =================

// gx_bf = bf16(relu(b + x@W0 + h1@W1 + h2@W2))
__global__ __launch_bounds__(256, 4)
void k_tag1_w(const float* __restrict__ x, const float* __restrict__ h1,
              const float* __restrict__ h2, const float* __restrict__ W,
              const float* __restrict__ b, unsigned short* __restrict__ out, int n) {
    int wv = (int)(((long long)blockIdx.x * blockDim.x + threadIdx.x) >> 6);
    int lane = threadIdx.x & 63;
    int i0 = wv * 4;
    if (i0 >= n) return;
    float v[4], acc[4];
    #pragma unroll
    for (int r = 0; r < 4; r++) {
        int i = (i0 + r < n) ? i0 + r : n - 1;
        float t = 0.f;
        if (lane < 5)                     t = x [(size_t)i * 5 + lane];
        else if (lane >= 8 && lane < 13)  t = h1[(size_t)i * 5 + lane - 8];
        else if (lane >= 16 && lane < 21) t = h2[(size_t)i * 5 + lane - 16];
        v[r] = t;
        acc[r] = b[lane];
    }
    #pragma unroll
    for (int m = 0; m < 3; m++) {
        #pragma unroll
        for (int k = 0; k < 5; k++) {
            float wk = W[(m * 5 + k) * 64 + lane];
            #pragma unroll
            for (int r = 0; r < 4; r++) acc[r] += bcast(v[r], m * 8 + k) * wk;
        }
    }
    #pragma unroll
    for (int r = 0; r < 4; r++)
        if (i0 + r < n) out[(size_t)(i0 + r) * 64 + lane] = f2bf(fmaxf(acc[r], 0.f));
}

// sx = relu(b + agg@Wrel + state@Wroot)   (fp32 out; only read by dense sage)
__global__ __launch_bounds__(256, 4)
void k_gc_w(const float* __restrict__ agg, const float* __restrict__ st,
            const float* __restrict__ Wrel, const float* __restrict__ Wroot,
            const float* __restrict__ b, float* __restrict__ out, int n) {
    int wv = (int)(((long long)blockIdx.x * blockDim.x + threadIdx.x) >> 6);
    int lane = threadIdx.x & 63;
    int i0 = wv * 4;
    if (i0 >= n) return;
    float xs[4], sr[4], acc[4];
    #pragma unroll
    for (int r = 0; r < 4; r++) {
        int i = (i0 + r < n) ? i0 + r : n - 1;
        xs[r] = agg[(size_t)i * 64 + lane];
        sr[r] = (lane < 6) ? st[(size_t)i * 6 + lane] : 0.f;
        acc[r] = b[lane];
    }
    #pragma unroll 8
    for (int k = 0; k < 64; k++) {
        float wk = Wrel[k * 64 + lane];
        #pragma unroll
        for (int r = 0; r < 4; r++) acc[r] += bcast(xs[r], k) * wk;
    }
    #pragma unroll
    for (int k = 0; k < 6; k++) {
        float wk = Wroot[k * 64 + lane];
        #pragma unroll
        for (int r = 0; r < 4; r++) acc[r] += bcast(sr[r], k) * wk;
    }
    #pragma unroll
    for (int r = 0; r < 4; r++)
        if (i0 + r < n) out[(size_t)(i0 + r) * 64 + lane] = fmaxf(acc[r], 0.f);
}

// sx2_bf = bf16(relu(bl + (ssum/max(cnt,1))@Wl + sx@Wr))
__global__ __launch_bounds__(256, 4)
void k_sage_w(const float* __restrict__ ssum, const int* __restrict__ rp,
              const float* __restrict__ sx, const float* __restrict__ Wl,
              const float* __restrict__ Wr, const float* __restrict__ bl,
              unsigned short* __restrict__ out, int n) {
    int wv = (int)(((long long)blockIdx.x * blockDim.x + threadIdx.x) >> 6);
    int lane = threadIdx.x & 63;
    int i0 = wv * 4;
    if (i0 >= n) return;
    float xs[4], ys[4], acc[4];
    #pragma unroll
    for (int r = 0; r < 4; r++) {
        int i = (i0 + r < n) ? i0 + r : n - 1;
        float cnt = (float)(rp[i + 1] - rp[i]);
        float rs = 1.f / fmaxf(cnt, 1.f);
        xs[r] = ssum[(size_t)i * 64 + lane] * rs;
        ys[r] = sx[(size_t)i * 64 + lane];
        acc[r] = bl[lane];
    }
    #pragma unroll 8
    for (int k = 0; k < 64; k++) {
        float wl = Wl[k * 64 + lane];
        float wr = Wr[k * 64 + lane];
        #pragma unroll
        for (int r = 0; r < 4; r++)
            acc[r] += bcast(xs[r], k) * wl + bcast(ys[r], k) * wr;
    }
    #pragma unroll
    for (int r = 0; r < 4; r++)
        if (i0 + r < n) out[(size_t)(i0 + r) * 64 + lane] = f2bf(fmaxf(acc[r], 0.f));
}

// INIT: out = bias + x@W ; else: out += x@W   (x rows bf16, W 64x64 fp32, out fp32)
template<bool INIT>
__global__ __launch_bounds__(256, 4)
void k_mm_w(const unsigned short* __restrict__ xbf, const float* __restrict__ W,
            const float* __restrict__ bias, float* __restrict__ out, int n) {
    int wv = (int)(((long long)blockIdx.x * blockDim.x + threadIdx.x) >> 6);
    int lane = threadIdx.x & 63;
    int i0 = wv * 4;
    if (i0 >= n) return;
    float xs[4], acc[4];
    #pragma unroll
    for (int r = 0; r < 4; r++) {
        int i = (i0 + r < n) ? i0 + r : n - 1;
        xs[r] = bf2f(xbf[(size_t)i * 64 + lane]);
        acc[r] = INIT ? bias[lane] : out[(size_t)i * 64 + lane];
    }
    #pragma unroll 8
    for (int k = 0; k < 64; k++) {
        float wk = W[k * 64 + lane];
        #pragma unroll
        for (int r = 0; r < 4; r++) acc[r] += bcast(xs[r], k) * wk;
    }
    #pragma unroll
    for (int r = 0; r < 4; r++)
        if (i0 + r < n) out[(size_t)(i0 + r) * 64 + lane] = acc[r];
}

__global__ void k_final(const float* __restrict__ x, const float* __restrict__ W,
                        const float* __restrict__ b, float* __restrict__ out, int n) {
    int t = blockIdx.x * blockDim.x + threadIdx.x;
    if (t >= n * 8) return;
    int i = t >> 3, o = t & 7;
    float acc = b[o];
    #pragma unroll 8
    for (int k = 0; k < 64; k++) acc += fmaxf(x[i * 64 + k], 0.f) * W[k * 8 + o];
    out[t] = acc;
}

static inline unsigned gblk(long long n) { return (unsigned)((n + BLK - 1) / BLK); }
static inline unsigned gwv4(long long n) { return gblk(((n + 3) / 4) * 64); }

extern "C" void kernel_launch(void* const* d_in, const int* in_sizes, int n_in,
                              void* d_out, int out_size, void* d_ws, size_t ws_size,
                              hipStream_t stream) {
    const float* game_x  = (const float*)d_in[0];
    const float* state_x = (const float*)d_in[1];
    const int*   ei_vv   = (const int*)d_in[2];
    const int*   ei_h    = (const int*)d_in[3];
    const float* ea_h    = (const float*)d_in[4];
    const int*   ei_in   = (const int*)d_in[5];
    const int*   ei_ss   = (const int*)d_in[6];
    const float* tag1_W  = (const float*)d_in[7];
    const float* tag1_b  = (const float*)d_in[8];
    const float* tag2_W  = (const float*)d_in[9];
    const float* tag2_b  = (const float*)d_in[10];
    const float* gc_Wrel = (const float*)d_in[11];
    const float* gc_b    = (const float*)d_in[12];
    const float* gc_Wroot= (const float*)d_in[13];
    const float* sage_Wl = (const float*)d_in[14];
    const float* sage_bl = (const float*)d_in[15];
    const float* sage_Wr = (const float*)d_in[16];
    const float* lin_W   = (const float*)d_in[17];
    const float* lin_b   = (const float*)d_in[18];

    const int NV  = in_sizes[0] / 5;
    const int NS  = in_sizes[1] / 6;
    const int EVV = in_sizes[2] / 2;
    const int EH  = in_sizes[3] / 2;
    const int EIN = in_sizes[5] / 2;
    const int ESS = in_sizes[6] / 2;

    const int *vv_s = ei_vv,  *vv_d = ei_vv + EVV;
    const int *h_s  = ei_h,   *h_d  = ei_h  + EH;
    const int *in_s = ei_in,  *in_d = ei_in + EIN;
    const int *ss_s = ei_ss,  *ss_d = ei_ss + ESS;

    // ---------------- workspace layout (4-byte words), ~72 MB ----------------
    float* wsf = (float*)d_ws;
    size_t o = 0;
    unsigned short* gx_bf = (unsigned short*)(wsf + o);   // NV x 64 bf16
    float* sx3 = wsf + o; o += (size_t)NV * 32;           // alias (NS*64 fp32 == NV*32 words)
    float* B1 = wsf + o; o += (size_t)NS * 64;            // cnt8 (phase0) | agg | ssum | hA_bf
    float* B2 = wsf + o; o += (size_t)NS * 64;            // base8 (phase0) | sx | hB_bf
    float* B4 = wsf + o; o += (size_t)NS * 32;            // h1v+h2v (NV*10) | sx2_bf (NS*32)
    int*  vvsrc = (int*)(wsf + o); o += (size_t)EVV;
    int*  sssrc = (int*)(wsf + o); o += (size_t)ESS;
    int*  insrc = (int*)(wsf + o); o += (size_t)EIN;
    int2* hsw   = (int2*)(wsf + o); o += (size_t)EH * 2;
    unsigned short* rkv = (unsigned short*)(wsf + o);
    unsigned short* rkh = rkv + EVV;
    unsigned short* rki = rkh + EH;
    unsigned short* rks = rki + EIN;
    o += ((size_t)EVV + EH + EIN + ESS + 1) / 2;
    int* rv = (int*)(wsf + o);    // NV+1
    int* rh = rv + NV + 1;        // NS+1
    int* ri = rh + NS + 1;        // NS+1
    int* rs = ri + NS + 1;        // NS+1
    float* dinv_v = (float*)(rs + NS + 1);  // NV
    float* dinv_s = dinv_v + NV;            // NS
    int* bsum = (int*)(dinv_s + NS);        // up to 1024

    // phase-0-only: 8 XCD-private histogram copies + per-XCD fill bases,
    // carved from B1/B2 (dead until stage B). 8*(NV+3*NS) ints = 2.0M <= NS*64.
    int* cnt8 = (int*)B1;
    int* cv8 = cnt8;
    int* ch8 = cv8 + (size_t)8 * NV;
    int* ci8 = ch8 + (size_t)8 * NS;
    int* cs8 = ci8 + (size_t)8 * NS;
    int* base8 = (int*)B2;
    int* bv8 = base8;
    int* bh8 = bv8 + (size_t)8 * NV;
    int* bi8 = bh8 + (size_t)8 * NS;
    int* bs8 = bi8 + (size_t)8 * NS;

    unsigned short* hA_bf  = (unsigned short*)B1;
    unsigned short* hB_bf  = (unsigned short*)B2;
    unsigned short* sx2_bf = (unsigned short*)B4;

    // ================= Phase 0: batched CSR build =================
    hipMemsetAsync(cnt8, 0, (size_t)8 * (NV + 3 * NS) * sizeof(int), stream);
    long long Etot = (long long)EVV + EH + EIN + ESS;
    k_hist_all<<<gblk(Etot), BLK, 0, stream>>>(vv_d, h_d, in_d, ss_d,
                                               cv8, ch8, ci8, cs8,
                                               rkv, rkh, rki, rks,
                                               EVV, EH, EIN, ESS, NV, NS);
    int nbv = (NV + 255) / 256, nbs = (NS + 255) / 256;
    int NB = nbv + 3 * nbs;
    k_scanb_all<<<NB, 256, 0, stream>>>(cv8, ch8, ci8, cs8, rv, rh, ri, rs,
                                        dinv_v, dinv_s, bsum, NV, NS, nbv, nbs);
    k_scant_all<<<4, 1024, 0, stream>>>(bsum, nbv, nbs);
    k_scana_all<<<NB, 256, 0, stream>>>(rv, rh, ri, rs,
                                        cv8, ch8, ci8, cs8,
                                        bv8, bh8, bi8, bs8,
                                        bsum, NV, NS, nbv, nbs, EVV, EH, EIN, ESS);
    k_fill_all<<<gblk(Etot), BLK, 0, stream>>>(
        vv_s, vv_d, rkv, bv8, vvsrc,
        h_s, h_d, ea_h, rkh, bh8, hsw,
        in_s, in_d, rki, bi8, insrc,
        ss_s, ss_d, rks, bs8, sssrc,
        EVV, EH, EIN, ESS, NV, NS);

    // ================= Stage A: TAGConv1 on v-v =================
    float* h1v = B4;
    float* h2v = B4 + (size_t)NV * 5;
    k_gather5<<<gblk(NV), BLK, 0, stream>>>(game_x, rv, vvsrc, dinv_v, h1v, NV);
    k_gather5<<<gblk(NV), BLK, 0, stream>>>(h1v,    rv, vvsrc, dinv_v, h2v, NV);
    k_tag1_w<<<gwv4(NV), BLK, 0, stream>>>(game_x, h1v, h2v, tag1_W, tag1_b, gx_bf, NV);

    // ================= Stage B: GraphConv (weighted) =================
    k_gather64<1, false><<<gblk((long long)NS * 64), BLK, 0, stream>>>(gx_bf, rh, nullptr, hsw, nullptr, B1, NS);
    k_gc_w<<<gwv4(NS), BLK, 0, stream>>>(B1, state_x, gc_Wrel, gc_Wroot, gc_b, B2, NS);

    // ================= Stage C: SAGE mean =================
    k_gather64<0, false><<<gblk((long long)NS * 64), BLK, 0, stream>>>(gx_bf, ri, insrc, nullptr, nullptr, B1, NS);
    k_sage_w<<<gwv4(NS), BLK, 0, stream>>>(B1, ri, B2, sage_Wl, sage_Wr, sage_bl, sx2_bf, NS);

    // ================= Stage D: TAGConv2 on s-s (K=3) =================
    // gx_bf dead -> sx3 alias; B1 (ssum) dead -> hA_bf; B2 (sx) dead -> hB_bf
    k_mm_w<true><<<gwv4(NS), BLK, 0, stream>>>(sx2_bf, tag2_W, tag2_b, sx3, NS);
    k_gather64<2, true><<<gblk((long long)NS * 64), BLK, 0, stream>>>(sx2_bf, rs, sssrc, nullptr, dinv_s, hA_bf, NS);
    k_mm_w<false><<<gwv4(NS), BLK, 0, stream>>>(hA_bf, tag2_W + 4096, nullptr, sx3, NS);
    k_gather64<2, true><<<gblk((long long)NS * 64), BLK, 0, stream>>>(hA_bf, rs, sssrc, nullptr, dinv_s, hB_bf, NS);
    k_mm_w<false><<<gwv4(NS), BLK, 0, stream>>>(hB_bf, tag2_W + 8192, nullptr, sx3, NS);
    k_gather64<2, true><<<gblk((long long)NS * 64), BLK, 0, stream>>>(hB_bf, rs, sssrc, nullptr, dinv_s, hA_bf, NS);
    k_mm_w<false><<<gwv4(NS), BLK, 0, stream>>>(hA_bf, tag2_W + 12288, nullptr, sx3, NS);

    // ================= Stage E: final linear (relu fused) =================
    k_final<<<gblk((long long)NS * 8), BLK, 0, stream>>>(sx3, lin_W, lin_b, (float*)d_out, NS);
}

// Round 2
// 540.737 us; speedup vs baseline: 1.2118x; 1.1633x over previous
//
#include <hip/hip_runtime.h>

#define BLK 256
#define ACH 4096   // edges per block in bin passes

// broadcast lane l of v across the wave (l wave-uniform; dynamic is legal)
__device__ __forceinline__ float bcast(float v, int l) {
    return __int_as_float(__builtin_amdgcn_readlane(__float_as_int(v), l));
}
// fp32 <-> bf16 (round-to-nearest-even)
__device__ __forceinline__ unsigned short f2bf(float f) {
    unsigned u = __float_as_uint(f);
    return (unsigned short)((u + 0x7FFFu + ((u >> 16) & 1u)) >> 16);
}
__device__ __forceinline__ float bf2f(unsigned short b) {
    return __uint_as_float(((unsigned)b) << 16);
}

// ================= atomic-free CSR build (two-level binned counting sort) ====
// Global atomics on gfx950 execute memory-side at ~25G/s (each = ~32B in
// WRITE_SIZE; scope annotations don't change the ISA) -> the old hist kernel
// was a hard 140us. This pipeline uses ONLY LDS atomics:
//   A1: per-4096-edge block, LDS histogram over dst>>shift bins; store counts
//       to T[bin][chunk] (transposed, plain stores).
//   scan(T) per graph (bin-major) -> T[b][c] = global base of each run; the
//       binned buffer becomes dst-bin-contiguous by construction.
//   A2: re-read edges, cur[bin] = T[b][c], ds_add_rtn assigns slot, write
//       packed (src<<shift | dst_local) (+weight for h) into binned buffers.
//   B:  one block per bin: LDS dst-local hist -> LDS scan -> rowptr + dinv +
//       final CSR scatter via LDS cursors. Bin data is L2-hot.

__global__ void k_binA1(const int* __restrict__ vd, const int* __restrict__ hd,
                        const int* __restrict__ id_, const int* __restrict__ sd,
                        int* __restrict__ Tv, int* __restrict__ Th,
                        int* __restrict__ Ti, int* __restrict__ Ts,
                        int ncv, int nch, int nci, int ncs,
                        int nbv_, int nbs_, int Ev, int Eh, int Ei, int Es) {
    __shared__ int cnt[512];
    int blk = blockIdx.x, t = threadIdx.x;
    const int* dd; int* T; int c, nc, nb, E, sf;
    if (blk < ncv)                 { dd = vd;  T = Tv; c = blk;               nc = ncv; nb = nbv_; E = Ev; sf = 8; }
    else if (blk < ncv + nch)      { dd = hd;  T = Th; c = blk - ncv;         nc = nch; nb = nbs_; E = Eh; sf = 7; }
    else if (blk < ncv + nch + nci){ dd = id_; T = Ti; c = blk - ncv - nch;   nc = nci; nb = nbs_; E = Ei; sf = 7; }
    else                           { dd = sd;  T = Ts; c = blk - ncv - nch - nci; nc = ncs; nb = nbs_; E = Es; sf = 7; }
    cnt[t] = 0; cnt[t + 256] = 0;
    __syncthreads();
    int p0 = c * ACH, p1 = min(E, p0 + ACH);
    for (int p = p0 + t; p < p1; p += 256) atomicAdd(&cnt[dd[p] >> sf], 1);
    __syncthreads();
    for (int b = t; b < nb; b += 256) T[(size_t)b * nc + c] = cnt[b];
}

// 3-level exclusive scan over the 4 concatenated T arrays (in place)
__global__ void k_sb2(int* __restrict__ T, int* __restrict__ bsum,
                      int L0, int L1, int L2, int L3,
                      int nB0, int nB1, int nB2, int nB3) {
    __shared__ int sh[256];
    int blk = blockIdx.x;
    int lb, off, L;
    if (blk < nB0)                  { lb = blk;                 off = 0;            L = L0; }
    else if (blk < nB0 + nB1)       { lb = blk - nB0;           off = L0;           L = L1; }
    else if (blk < nB0 + nB1 + nB2) { lb = blk - nB0 - nB1;     off = L0 + L1;      L = L2; }
    else                            { lb = blk - nB0 - nB1 - nB2; off = L0 + L1 + L2; L = L3; }
    int i = lb * 256 + threadIdx.x;
    int v = (i < L) ? T[off + i] : 0;
    sh[threadIdx.x] = v; __syncthreads();
    for (int o2 = 1; o2 < 256; o2 <<= 1) {
        int tmp = (threadIdx.x >= o2) ? sh[threadIdx.x - o2] : 0;
        __syncthreads();
        sh[threadIdx.x] += tmp; __syncthreads();
    }
    if (i < L) T[off + i] = sh[threadIdx.x] - v;
    if (threadIdx.x == 255) bsum[blk] = sh[255];
}

__global__ void k_st2(int* __restrict__ bsum, int nB0, int nB1, int nB2, int nB3) {
    __shared__ int sh[1024];
    int g = blockIdx.x;
    int off = (g == 0) ? 0 : (g == 1) ? nB0 : (g == 2) ? nB0 + nB1 : nB0 + nB1 + nB2;
    int nb  = (g == 0) ? nB0 : (g == 1) ? nB1 : (g == 2) ? nB2 : nB3;
    int tid = threadIdx.x;
    int v = (tid < nb) ? bsum[off + tid] : 0;
    sh[tid] = v; __syncthreads();
    for (int o2 = 1; o2 < 1024; o2 <<= 1) {
        int t = (tid >= o2) ? sh[tid - o2] : 0;
        __syncthreads();
        sh[tid] += t; __syncthreads();
    }
    if (tid < nb) bsum[off + tid] = sh[tid] - v;
}

__global__ void k_sa2(int* __restrict__ T, const int* __restrict__ bsum,
                      int L0, int L1, int L2, int L3,
                      int nB0, int nB1, int nB2, int nB3) {
    int blk = blockIdx.x;
    int lb, off, L;
    if (blk < nB0)                  { lb = blk;                 off = 0;            L = L0; }
    else if (blk < nB0 + nB1)       { lb = blk - nB0;           off = L0;           L = L1; }
    else if (blk < nB0 + nB1 + nB2) { lb = blk - nB0 - nB1;     off = L0 + L1;      L = L2; }
    else                            { lb = blk - nB0 - nB1 - nB2; off = L0 + L1 + L2; L = L3; }
    int i = lb * 256 + threadIdx.x;
    if (i < L) T[off + i] += bsum[blk];
}

__global__ void k_binA2(const int* __restrict__ vs, const int* __restrict__ vd,
                        const int* __restrict__ hs, const int* __restrict__ hd,
                        const float* __restrict__ hw,
                        const int* __restrict__ is_, const int* __restrict__ id_,
                        const int* __restrict__ ss_, const int* __restrict__ sd,
                        const int* __restrict__ Tv, const int* __restrict__ Th,
                        const int* __restrict__ Ti, const int* __restrict__ Ts,
                        unsigned* __restrict__ vvbin, int2* __restrict__ hbin,
                        unsigned* __restrict__ inbin, unsigned* __restrict__ ssbin,
                        int ncv, int nch, int nci, int ncs,
                        int nbv_, int nbs_, int Ev, int Eh, int Ei, int Es) {
    __shared__ int cur[512];
    int blk = blockIdx.x, t = threadIdx.x;
    int g, c, nc, nb, E, sf; const int* T; const int* srcp; const int* dstp;
    if (blk < ncv)                 { g = 0; c = blk;               nc = ncv; nb = nbv_; E = Ev; sf = 8; T = Tv; srcp = vs;  dstp = vd; }
    else if (blk < ncv + nch)      { g = 1; c = blk - ncv;         nc = nch; nb = nbs_; E = Eh; sf = 7; T = Th; srcp = hs;  dstp = hd; }
    else if (blk < ncv + nch + nci){ g = 2; c = blk - ncv - nch;   nc = nci; nb = nbs_; E = Ei; sf = 7; T = Ti; srcp = is_; dstp = id_; }
    else                           { g = 3; c = blk - ncv - nch - nci; nc = ncs; nb = nbs_; E = Es; sf = 7; T = Ts; srcp = ss_; dstp = sd; }
    for (int b = t; b < nb; b += 256) cur[b] = T[(size_t)b * nc + c];
    __syncthreads();
    int p0 = c * ACH, p1 = min(E, p0 + ACH);
    int msk = (1 << sf) - 1;
    for (int p = p0 + t; p < p1; p += 256) {
        int dv = dstp[p];
        int b = dv >> sf;
        int pos = atomicAdd(&cur[b], 1);
        unsigned pk = ((unsigned)srcp[p] << sf) | (unsigned)(dv & msk);
        if (g == 0)      vvbin[pos] = pk;
        else if (g == 1) hbin[pos]  = make_int2((int)pk, __float_as_int(hw[p]));
        else if (g == 2) inbin[pos] = pk;
        else             ssbin[pos] = pk;
    }
}

__global__ void k_binB(const unsigned* __restrict__ vvbin, const int2* __restrict__ hbin,
                       const unsigned* __restrict__ inbin, const unsigned* __restrict__ ssbin,
                       const int* __restrict__ Tv, const int* __restrict__ Th,
                       const int* __restrict__ Ti, const int* __restrict__ Ts,
                       int* __restrict__ rv, int* __restrict__ rh,
                       int* __restrict__ ri, int* __restrict__ rs,
                       float* __restrict__ dinv_v, float* __restrict__ dinv_s,
                       int* __restrict__ vvsrc, int2* __restrict__ hsw,
                       int* __restrict__ insrc, int* __restrict__ sssrc,
                       int ncv, int nch, int nci, int ncs,
                       int nbv_, int nbs_, int nv, int ns,
                       int Ev, int Eh, int Ei, int Es) {
    __shared__ int cnt[256]; __shared__ int pre[256]; __shared__ int cur[256];
    int blk = blockIdx.x, t = threadIdx.x;
    int g, b, nb, nc, sf, n, E; const int* T; int* rp;
    if (blk < nbv_)                 { g = 0; b = blk;                 nb = nbv_; nc = ncv; sf = 8; n = nv; E = Ev; T = Tv; rp = rv; }
    else if (blk < nbv_ + nbs_)     { g = 1; b = blk - nbv_;          nb = nbs_; nc = nch; sf = 7; n = ns; E = Eh; T = Th; rp = rh; }
    else if (blk < nbv_ + 2 * nbs_) { g = 2; b = blk - nbv_ - nbs_;   nb = nbs_; nc = nci; sf = 7; n = ns; E = Ei; T = Ti; rp = ri; }
    else                            { g = 3; b = blk - nbv_ - 2 * nbs_; nb = nbs_; nc = ncs; sf = 7; n = ns; E = Es; T = Ts; rp = rs; }
    int W = 1 << sf, msk = W - 1;
    int e0 = T[(size_t)b * nc];
    int e1 = (b + 1 < nb) ? T[(size_t)(b + 1) * nc] : E;
    cnt[t] = 0; __syncthreads();
    for (int p = e0 + t; p < e1; p += 256) {
        unsigned pk = (g == 1) ? (unsigned)hbin[p].x
                    : (g == 0) ? vvbin[p] : (g == 2) ? inbin[p] : ssbin[p];
        atomicAdd(&cnt[pk & msk], 1);
    }
    __syncthreads();
    int v = cnt[t];
    pre[t] = v; __syncthreads();
    for (int o2 = 1; o2 < 256; o2 <<= 1) {
        int tmp = (t >= o2) ? pre[t - o2] : 0;
        __syncthreads();
        pre[t] += tmp; __syncthreads();
    }
    int excl = pre[t] - v;
    int d = b * W + t;
    if (t < W && d < n) {
        rp[d] = e0 + excl;
        if (g == 0)      dinv_v[d] = v > 0 ? rsqrtf((float)v) : 0.f;
        else if (g == 3) dinv_s[d] = v > 0 ? rsqrtf((float)v) : 0.f;
    }
    cur[t] = e0 + excl;
    __syncthreads();
    for (int p = e0 + t; p < e1; p += 256) {
        if (g == 1) {
            int2 r = hbin[p];
            unsigned pk = (unsigned)r.x;
            int pos = atomicAdd(&cur[pk & msk], 1);
            hsw[pos] = make_int2((int)(pk >> sf), r.y);
        } else {
            unsigned pk = (g == 0) ? vvbin[p] : (g == 2) ? inbin[p] : ssbin[p];
            int pos = atomicAdd(&cur[pk & msk], 1);
            int sv = (int)(pk >> sf);
            if (g == 0)      vvsrc[pos] = sv;
            else if (g == 2) insrc[pos] = sv;
            else             sssrc[pos] = sv;
        }
    }
    if (b == 0 && t == 0) rp[n] = E;
}

// ================= gathers =================

__global__ void k_gather5(const float* __restrict__ x, const int* __restrict__ rowptr,
                          const int* __restrict__ csr_src, const float* __restrict__ dinv,
                          float* __restrict__ out, int n) {
    int d = blockIdx.x * blockDim.x + threadIdx.x;
    if (d >= n) return;
    int b = rowptr[d], e = rowptr[d + 1];
    float dd = dinv[d];
    float a0 = 0, a1 = 0, a2 = 0, a3 = 0, a4 = 0;
    int p = b;
    for (; p + 4 <= e; p += 4) {
        int s0 = csr_src[p], s1 = csr_src[p+1], s2 = csr_src[p+2], s3 = csr_src[p+3];
        const float* x0 = x + (size_t)s0 * 5;
        const float* x1 = x + (size_t)s1 * 5;
        const float* x2 = x + (size_t)s2 * 5;
        const float* x3 = x + (size_t)s3 * 5;
        float w0 = dd * dinv[s0], w1 = dd * dinv[s1], w2 = dd * dinv[s2], w3 = dd * dinv[s3];
        a0 += x0[0]*w0 + x1[0]*w1 + x2[0]*w2 + x3[0]*w3;
        a1 += x0[1]*w0 + x1[1]*w1 + x2[1]*w2 + x3[1]*w3;
        a2 += x0[2]*w0 + x1[2]*w1 + x2[2]*w2 + x3[2]*w3;
        a3 += x0[3]*w0 + x1[3]*w1 + x2[3]*w2 + x3[3]*w3;
        a4 += x0[4]*w0 + x1[4]*w1 + x2[4]*w2 + x3[4]*w3;
    }
    for (; p < e; p++) {
        int s = csr_src[p];
        float w = dd * dinv[s];
        const float* xp = x + (size_t)s * 5;
        a0 += xp[0]*w; a1 += xp[1]*w; a2 += xp[2]*w; a3 += xp[3]*w; a4 += xp[4]*w;
    }
    float* op = out + (size_t)d * 5;
    op[0] = a0; op[1] = a1; op[2] = a2; op[3] = a3; op[4] = a4;
}

// 64-ch gather over bf16 rows: wave per dst row; 4 groups x 16 lanes x ushort4(8B);
// 4-edge-deep MLP; fp32 accumulate.
// MODE: 0 = plain sum, 1 = per-edge weight (int2 packed), 2 = symmetric gcn norm
// OUTBF: write bf16 row (for next gather hop) vs fp32 row
template<int MODE, bool OUTBF>
__global__ void k_gather64(const unsigned short* __restrict__ xbf, const int* __restrict__ rowptr,
                           const int* __restrict__ csr_src, const int2* __restrict__ csr_sw,
                           const float* __restrict__ dinv, void* __restrict__ outp, int n) {
    int wid = (int)(((long long)blockIdx.x * blockDim.x + threadIdx.x) >> 6);
    if (wid >= n) return;
    int lane = threadIdx.x & 63;
    int g = lane >> 4, q = lane & 15;
    int b = rowptr[wid], e = rowptr[wid + 1];
    float dd = (MODE == 2) ? dinv[wid] : 0.f;
    float4 acc = make_float4(0.f, 0.f, 0.f, 0.f);
    int p = b + g;
    for (; p + 12 < e; p += 16) {
        int s0, s1, s2, s3;
        float w0 = 1.f, w1 = 1.f, w2 = 1.f, w3 = 1.f;
        if (MODE == 1) {
            int2 e0 = csr_sw[p], e1 = csr_sw[p+4], e2 = csr_sw[p+8], e3 = csr_sw[p+12];
            s0 = e0.x; w0 = __int_as_float(e0.y);
            s1 = e1.x; w1 = __int_as_float(e1.y);
            s2 = e2.x; w2 = __int_as_float(e2.y);
            s3 = e3.x; w3 = __int_as_float(e3.y);
        } else {
            s0 = csr_src[p]; s1 = csr_src[p+4]; s2 = csr_src[p+8]; s3 = csr_src[p+12];
            if (MODE == 2) {
                w0 = dd * dinv[s0]; w1 = dd * dinv[s1];
                w2 = dd * dinv[s2]; w3 = dd * dinv[s3];
            }
        }
        ushort4 u0 = ((const ushort4*)(xbf + (size_t)s0 * 64))[q];
        ushort4 u1 = ((const ushort4*)(xbf + (size_t)s1 * 64))[q];
        ushort4 u2 = ((const ushort4*)(xbf + (size_t)s2 * 64))[q];
        ushort4 u3 = ((const ushort4*)(xbf + (size_t)s3 * 64))[q];
        acc.x += bf2f(u0.x)*w0 + bf2f(u1.x)*w1 + bf2f(u2.x)*w2 + bf2f(u3.x)*w3;
        acc.y += bf2f(u0.y)*w0 + bf2f(u1.y)*w1 + bf2f(u2.y)*w2 + bf2f(u3.y)*w3;
        acc.z += bf2f(u0.z)*w0 + bf2f(u1.z)*w1 + bf2f(u2.z)*w2 + bf2f(u3.z)*w3;
        acc.w += bf2f(u0.w)*w0 + bf2f(u1.w)*w1 + bf2f(u2.w)*w2 + bf2f(u3.w)*w3;
    }
    for (; p < e; p += 4) {
        int s; float w = 1.f;
        if (MODE == 1) { int2 e0 = csr_sw[p]; s = e0.x; w = __int_as_float(e0.y); }
        else { s = csr_src[p]; if (MODE == 2) w = dd * dinv[s]; }
        ushort4 u = ((const ushort4*)(xbf + (size_t)s * 64))[q];
        acc.x += bf2f(u.x)*w; acc.y += bf2f(u.y)*w;
        acc.z += bf2f(u.z)*w; acc.w += bf2f(u.w)*w;
    }
    #pragma unroll
    for (int off = 16; off < 64; off <<= 1) {
        acc.x += __shfl_xor(acc.x, off, 64);
        acc.y += __shfl_xor(acc.y, off, 64);
        acc.z += __shfl_xor(acc.z, off, 64);
        acc.w += __shfl_xor(acc.w, off, 64);
    }
    if (g == 0) {
        if (OUTBF) {
            ushort4 ov;
            ov.x = f2bf(acc.x); ov.y = f2bf(acc.y); ov.z = f2bf(acc.z); ov.w = f2bf(acc.w);
            ((ushort4*)outp)[(size_t)wid * 16 + q] = ov;
        } else {
            ((float4*)outp)[(size_t)wid * 16 + q] = acc;
        }
    }
}

// ================= dense combines (wave-tiled register GEMMs) =================

// gx_bf = bf16(relu(b + x@W0 + h1@W1 + h2@W2))
__global__ __launch_bounds__(256, 4)
void k_tag1_w(const float* __restrict__ x, const float* __restrict__ h1,
              const float* __restrict__ h2, const float* __restrict__ W,
              const float* __restrict__ b, unsigned short* __restrict__ out, int n) {
    int wv = (int)(((long long)blockIdx.x * blockDim.x + threadIdx.x) >> 6);
    int lane = threadIdx.x & 63;
    int i0 = wv * 4;
    if (i0 >= n) return;
    float v[4], acc[4];
    #pragma unroll
    for (int r = 0; r < 4; r++) {
        int i = (i0 + r < n) ? i0 + r : n - 1;
        float t = 0.f;
        if (lane < 5)                     t = x [(size_t)i * 5 + lane];
        else if (lane >= 8 && lane < 13)  t = h1[(size_t)i * 5 + lane - 8];
        else if (lane >= 16 && lane < 21) t = h2[(size_t)i * 5 + lane - 16];
        v[r] = t;
        acc[r] = b[lane];
    }
    #pragma unroll
    for (int m = 0; m < 3; m++) {
        #pragma unroll
        for (int k = 0; k < 5; k++) {
            float wk = W[(m * 5 + k) * 64 + lane];
            #pragma unroll
            for (int r = 0; r < 4; r++) acc[r] += bcast(v[r], m * 8 + k) * wk;
        }
    }
    #pragma unroll
    for (int r = 0; r < 4; r++)
        if (i0 + r < n) out[(size_t)(i0 + r) * 64 + lane] = f2bf(fmaxf(acc[r], 0.f));
}

// sx = relu(b + agg@Wrel + state@Wroot)   (fp32 out; only read by dense sage)
__global__ __launch_bounds__(256, 4)
void k_gc_w(const float* __restrict__ agg, const float* __restrict__ st,
            const float* __restrict__ Wrel, const float* __restrict__ Wroot,
            const float* __restrict__ b, float* __restrict__ out, int n) {
    int wv = (int)(((long long)blockIdx.x * blockDim.x + threadIdx.x) >> 6);
    int lane = threadIdx.x & 63;
    int i0 = wv * 4;
    if (i0 >= n) return;
    float xs[4], sr[4], acc[4];
    #pragma unroll
    for (int r = 0; r < 4; r++) {
        int i = (i0 + r < n) ? i0 + r : n - 1;
        xs[r] = agg[(size_t)i * 64 + lane];
        sr[r] = (lane < 6) ? st[(size_t)i * 6 + lane] : 0.f;
        acc[r] = b[lane];
    }
    #pragma unroll 8
    for (int k = 0; k < 64; k++) {
        float wk = Wrel[k * 64 + lane];
        #pragma unroll
        for (int r = 0; r < 4; r++) acc[r] += bcast(xs[r], k) * wk;
    }
    #pragma unroll
    for (int k = 0; k < 6; k++) {
        float wk = Wroot[k * 64 + lane];
        #pragma unroll
        for (int r = 0; r < 4; r++) acc[r] += bcast(sr[r], k) * wk;
    }
    #pragma unroll
    for (int r = 0; r < 4; r++)
        if (i0 + r < n) out[(size_t)(i0 + r) * 64 + lane] = fmaxf(acc[r], 0.f);
}

// sx2_bf = bf16(relu(bl + (ssum/max(cnt,1))@Wl + sx@Wr))
__global__ __launch_bounds__(256, 4)
void k_sage_w(const float* __restrict__ ssum, const int* __restrict__ rp,
              const float* __restrict__ sx, const float* __restrict__ Wl,
              const float* __restrict__ Wr, const float* __restrict__ bl,
              unsigned short* __restrict__ out, int n) {
    int wv = (int)(((long long)blockIdx.x * blockDim.x + threadIdx.x) >> 6);
    int lane = threadIdx.x & 63;
    int i0 = wv * 4;
    if (i0 >= n) return;
    float xs[4], ys[4], acc[4];
    #pragma unroll
    for (int r = 0; r < 4; r++) {
        int i = (i0 + r < n) ? i0 + r : n - 1;
        float cnt = (float)(rp[i + 1] - rp[i]);
        float rs = 1.f / fmaxf(cnt, 1.f);
        xs[r] = ssum[(size_t)i * 64 + lane] * rs;
        ys[r] = sx[(size_t)i * 64 + lane];
        acc[r] = bl[lane];
    }
    #pragma unroll 8
    for (int k = 0; k < 64; k++) {
        float wl = Wl[k * 64 + lane];
        float wr = Wr[k * 64 + lane];
        #pragma unroll
        for (int r = 0; r < 4; r++)
            acc[r] += bcast(xs[r], k) * wl + bcast(ys[r], k) * wr;
    }
    #pragma unroll
    for (int r = 0; r < 4; r++)
        if (i0 + r < n) out[(size_t)(i0 + r) * 64 + lane] = f2bf(fmaxf(acc[r], 0.f));
}

// INIT: out = bias + x@W ; else: out += x@W   (x rows bf16, W 64x64 fp32, out fp32)
template<bool INIT>
__global__ __launch_bounds__(256, 4)
void k_mm_w(const unsigned short* __restrict__ xbf, const float* __restrict__ W,
            const float* __restrict__ bias, float* __restrict__ out, int n) {
    int wv = (int)(((long long)blockIdx.x * blockDim.x + threadIdx.x) >> 6);
    int lane = threadIdx.x & 63;
    int i0 = wv * 4;
    if (i0 >= n) return;
    float xs[4], acc[4];
    #pragma unroll
    for (int r = 0; r < 4; r++) {
        int i = (i0 + r < n) ? i0 + r : n - 1;
        xs[r] = bf2f(xbf[(size_t)i * 64 + lane]);
        acc[r] = INIT ? bias[lane] : out[(size_t)i * 64 + lane];
    }
    #pragma unroll 8
    for (int k = 0; k < 64; k++) {
        float wk = W[k * 64 + lane];
        #pragma unroll
        for (int r = 0; r < 4; r++) acc[r] += bcast(xs[r], k) * wk;
    }
    #pragma unroll
    for (int r = 0; r < 4; r++)
        if (i0 + r < n) out[(size_t)(i0 + r) * 64 + lane] = acc[r];
}

__global__ void k_final(const float* __restrict__ x, const float* __restrict__ W,
                        const float* __restrict__ b, float* __restrict__ out, int n) {
    int t = blockIdx.x * blockDim.x + threadIdx.x;
    if (t >= n * 8) return;
    int i = t >> 3, o = t & 7;
    float acc = b[o];
    #pragma unroll 8
    for (int k = 0; k < 64; k++) acc += fmaxf(x[i * 64 + k], 0.f) * W[k * 8 + o];
    out[t] = acc;
}

static inline unsigned gblk(long long n) { return (unsigned)((n + BLK - 1) / BLK); }
static inline unsigned gwv4(long long n) { return gblk(((n + 3) / 4) * 64); }

extern "C" void kernel_launch(void* const* d_in, const int* in_sizes, int n_in,
                              void* d_out, int out_size, void* d_ws, size_t ws_size,
                              hipStream_t stream) {
    const float* game_x  = (const float*)d_in[0];
    const float* state_x = (const float*)d_in[1];
    const int*   ei_vv   = (const int*)d_in[2];
    const int*   ei_h    = (const int*)d_in[3];
    const float* ea_h    = (const float*)d_in[4];
    const int*   ei_in   = (const int*)d_in[5];
    const int*   ei_ss   = (const int*)d_in[6];
    const float* tag1_W  = (const float*)d_in[7];
    const float* tag1_b  = (const float*)d_in[8];
    const float* tag2_W  = (const float*)d_in[9];
    const float* tag2_b  = (const float*)d_in[10];
    const float* gc_Wrel = (const float*)d_in[11];
    const float* gc_b    = (const float*)d_in[12];
    const float* gc_Wroot= (const float*)d_in[13];
    const float* sage_Wl = (const float*)d_in[14];
    const float* sage_bl = (const float*)d_in[15];
    const float* sage_Wr = (const float*)d_in[16];
    const float* lin_W   = (const float*)d_in[17];
    const float* lin_b   = (const float*)d_in[18];

    const int NV  = in_sizes[0] / 5;
    const int NS  = in_sizes[1] / 6;
    const int EVV = in_sizes[2] / 2;
    const int EH  = in_sizes[3] / 2;
    const int EIN = in_sizes[5] / 2;
    const int ESS = in_sizes[6] / 2;

    const int *vv_s = ei_vv,  *vv_d = ei_vv + EVV;
    const int *h_s  = ei_h,   *h_d  = ei_h  + EH;
    const int *in_s = ei_in,  *in_d = ei_in + EIN;
    const int *ss_s = ei_ss,  *ss_d = ei_ss + ESS;

    // bin geometry
    const int ncv = (EVV + ACH - 1) / ACH;
    const int nch = (EH  + ACH - 1) / ACH;
    const int nci = (EIN + ACH - 1) / ACH;
    const int ncs = (ESS + ACH - 1) / ACH;
    const int nbv_ = (NV + 255) >> 8;   // bin width 256 over NV dsts
    const int nbs_ = (NS + 127) >> 7;   // bin width 128 over NS dsts
    const int Lv = nbv_ * ncv, Lh = nbs_ * nch, Li = nbs_ * nci, Ls = nbs_ * ncs;
    const int nB0 = (Lv + 255) / 256, nB1 = (Lh + 255) / 256,
              nB2 = (Li + 255) / 256, nB3 = (Ls + 255) / 256;

    // ---------------- workspace layout (4-byte words) ----------------
    float* wsf = (float*)d_ws;
    size_t o = 0;
    unsigned short* gx_bf = (unsigned short*)(wsf + o);   // NV x 64 bf16
    float* sx3 = wsf + o; o += (size_t)NV * 32;           // alias (NS*64 fp32 == NV*32 words)
    float* B1 = wsf + o; o += (size_t)NS * 64;            // binned vv|in|ss (phase0) | agg | ssum | hA_bf
    float* B2 = wsf + o; o += (size_t)NS * 64;            // binned h (phase0) | sx | hB_bf
    float* B4 = wsf + o; o += (size_t)NS * 32;            // h1v+h2v (NV*10) | sx2_bf (NS*32)
    int*  vvsrc = (int*)(wsf + o); o += (size_t)EVV;
    int*  sssrc = (int*)(wsf + o); o += (size_t)ESS;
    int*  insrc = (int*)(wsf + o); o += (size_t)EIN;
    int2* hsw   = (int2*)(wsf + o); o += (size_t)EH * 2;
    int* T_all = (int*)(wsf + o); o += (size_t)(Lv + Lh + Li + Ls);
    int* bsum  = (int*)(wsf + o); o += 2048;              // scan block sums
    int* rv = (int*)(wsf + o); o += (size_t)NV + 1;
    int* rh = (int*)(wsf + o); o += (size_t)NS + 1;
    int* ri = (int*)(wsf + o); o += (size_t)NS + 1;
    int* rs = (int*)(wsf + o); o += (size_t)NS + 1;
    float* dinv_v = wsf + o; o += (size_t)NV;
    float* dinv_s = wsf + o; o += (size_t)NS;

    int* Tv = T_all;
    int* Th = Tv + Lv;
    int* Ti = Th + Lh;
    int* Ts = Ti + Li;

    // phase-0 binned edge buffers alias B1/B2 (dead until stage B):
    // B1 holds vv(EVV) + in(EIN) + ss(ESS) u32 = 2.5M <= NS*64 = 3.2M words
    // B2 holds h (EH int2) = 2M words <= 3.2M
    unsigned* vvbin = (unsigned*)B1;
    unsigned* inbin = vvbin + EVV;
    unsigned* ssbin = inbin + EIN;
    int2* hbin = (int2*)B2;

    unsigned short* hA_bf  = (unsigned short*)B1;
    unsigned short* hB_bf  = (unsigned short*)B2;
    unsigned short* sx2_bf = (unsigned short*)B4;

    // ================= Phase 0: atomic-free batched CSR build =================
    int nchunks = ncv + nch + nci + ncs;
    int nbins   = nbv_ + 3 * nbs_;
    int nBtot   = nB0 + nB1 + nB2 + nB3;
    k_binA1<<<nchunks, 256, 0, stream>>>(vv_d, h_d, in_d, ss_d, Tv, Th, Ti, Ts,
                                         ncv, nch, nci, ncs, nbv_, nbs_,
                                         EVV, EH, EIN, ESS);
    k_sb2<<<nBtot, 256, 0, stream>>>(T_all, bsum, Lv, Lh, Li, Ls, nB0, nB1, nB2, nB3);
    k_st2<<<4, 1024, 0, stream>>>(bsum, nB0, nB1, nB2, nB3);
    k_sa2<<<nBtot, 256, 0, stream>>>(T_all, bsum, Lv, Lh, Li, Ls, nB0, nB1, nB2, nB3);
    k_binA2<<<nchunks, 256, 0, stream>>>(vv_s, vv_d, h_s, h_d, ea_h,
                                         in_s, in_d, ss_s, ss_d,
                                         Tv, Th, Ti, Ts,
                                         vvbin, hbin, inbin, ssbin,
                                         ncv, nch, nci, ncs, nbv_, nbs_,
                                         EVV, EH, EIN, ESS);
    k_binB<<<nbins, 256, 0, stream>>>(vvbin, hbin, inbin, ssbin,
                                      Tv, Th, Ti, Ts,
                                      rv, rh, ri, rs, dinv_v, dinv_s,
                                      vvsrc, hsw, insrc, sssrc,
                                      ncv, nch, nci, ncs, nbv_, nbs_,
                                      NV, NS, EVV, EH, EIN, ESS);

    // ================= Stage A: TAGConv1 on v-v =================
    float* h1v = B4;
    float* h2v = B4 + (size_t)NV * 5;
    k_gather5<<<gblk(NV), BLK, 0, stream>>>(game_x, rv, vvsrc, dinv_v, h1v, NV);
    k_gather5<<<gblk(NV), BLK, 0, stream>>>(h1v,    rv, vvsrc, dinv_v, h2v, NV);
    k_tag1_w<<<gwv4(NV), BLK, 0, stream>>>(game_x, h1v, h2v, tag1_W, tag1_b, gx_bf, NV);

    // ================= Stage B: GraphConv (weighted) =================
    k_gather64<1, false><<<gblk((long long)NS * 64), BLK, 0, stream>>>(gx_bf, rh, nullptr, hsw, nullptr, B1, NS);
    k_gc_w<<<gwv4(NS), BLK, 0, stream>>>(B1, state_x, gc_Wrel, gc_Wroot, gc_b, B2, NS);

    // ================= Stage C: SAGE mean =================
    k_gather64<0, false><<<gblk((long long)NS * 64), BLK, 0, stream>>>(gx_bf, ri, insrc, nullptr, nullptr, B1, NS);
    k_sage_w<<<gwv4(NS), BLK, 0, stream>>>(B1, ri, B2, sage_Wl, sage_Wr, sage_bl, sx2_bf, NS);

    // ================= Stage D: TAGConv2 on s-s (K=3) =================
    // gx_bf dead -> sx3 alias; B1 (ssum) dead -> hA_bf; B2 (sx) dead -> hB_bf
    k_mm_w<true><<<gwv4(NS), BLK, 0, stream>>>(sx2_bf, tag2_W, tag2_b, sx3, NS);
    k_gather64<2, true><<<gblk((long long)NS * 64), BLK, 0, stream>>>(sx2_bf, rs, sssrc, nullptr, dinv_s, hA_bf, NS);
    k_mm_w<false><<<gwv4(NS), BLK, 0, stream>>>(hA_bf, tag2_W + 4096, nullptr, sx3, NS);
    k_gather64<2, true><<<gblk((long long)NS * 64), BLK, 0, stream>>>(hA_bf, rs, sssrc, nullptr, dinv_s, hB_bf, NS);
    k_mm_w<false><<<gwv4(NS), BLK, 0, stream>>>(hB_bf, tag2_W + 8192, nullptr, sx3, NS);
    k_gather64<2, true><<<gblk((long long)NS * 64), BLK, 0, stream>>>(hB_bf, rs, sssrc, nullptr, dinv_s, hA_bf, NS);
    k_mm_w<false><<<gwv4(NS), BLK, 0, stream>>>(hA_bf, tag2_W + 12288, nullptr, sx3, NS);

    // ================= Stage E: final linear (relu fused) =================
    k_final<<<gblk((long long)NS * 8), BLK, 0, stream>>>(sx3, lin_W, lin_b, (float*)d_out, NS);
}

// Round 3
// 499.180 us; speedup vs baseline: 1.3127x; 1.0832x over previous
//
#include <hip/hip_runtime.h>

#define BLK 256
#define ACH 4096   // edges per block in bin passes

// broadcast lane l of v across the wave (l wave-uniform; dynamic is legal)
__device__ __forceinline__ float bcast(float v, int l) {
    return __int_as_float(__builtin_amdgcn_readlane(__float_as_int(v), l));
}
// fp32 <-> bf16 (round-to-nearest-even)
__device__ __forceinline__ unsigned short f2bf(float f) {
    unsigned u = __float_as_uint(f);
    return (unsigned short)((u + 0x7FFFu + ((u >> 16) & 1u)) >> 16);
}
__device__ __forceinline__ float bf2f(unsigned short b) {
    return __uint_as_float(((unsigned)b) << 16);
}

// ================= atomic-free CSR build (two-level binned counting sort) ====
//   A1: per-4096-edge block, LDS histogram over dst>>shift bins; store counts
//       to T[bin][chunk] (transposed, plain stores).
//   scan(T) per graph (bin-major) -> T[b][c] = global base of each run.
//   A2: register-stage edges, LDS counting sort by bin, then stream LDS out
//       so global writes are piecewise-contiguous runs (kills the 4.4x write
//       amplification the naive per-lane scatter had: 80MB -> ~payload).
//   B:  one block per bin: LDS dst-local hist -> LDS scan -> rowptr + dinv +
//       final CSR scatter via LDS cursors. Bin data is L2-hot.

__global__ void k_binA1(const int* __restrict__ vd, const int* __restrict__ hd,
                        const int* __restrict__ id_, const int* __restrict__ sd,
                        int* __restrict__ Tv, int* __restrict__ Th,
                        int* __restrict__ Ti, int* __restrict__ Ts,
                        int ncv, int nch, int nci, int ncs,
                        int nbv_, int nbs_, int Ev, int Eh, int Ei, int Es) {
    __shared__ int cnt[512];
    int blk = blockIdx.x, t = threadIdx.x;
    const int* dd; int* T; int c, nc, nb, E, sf;
    if (blk < ncv)                 { dd = vd;  T = Tv; c = blk;               nc = ncv; nb = nbv_; E = Ev; sf = 8; }
    else if (blk < ncv + nch)      { dd = hd;  T = Th; c = blk - ncv;         nc = nch; nb = nbs_; E = Eh; sf = 7; }
    else if (blk < ncv + nch + nci){ dd = id_; T = Ti; c = blk - ncv - nch;   nc = nci; nb = nbs_; E = Ei; sf = 7; }
    else                           { dd = sd;  T = Ts; c = blk - ncv - nch - nci; nc = ncs; nb = nbs_; E = Es; sf = 7; }
    cnt[t] = 0; cnt[t + 256] = 0;
    __syncthreads();
    int p0 = c * ACH, p1 = min(E, p0 + ACH);
    for (int p = p0 + t; p < p1; p += 256) atomicAdd(&cnt[dd[p] >> sf], 1);
    __syncthreads();
    for (int b = t; b < nb; b += 256) T[(size_t)b * nc + c] = cnt[b];
}

// 3-level exclusive scan over the 4 concatenated T arrays (in place)
__global__ void k_sb2(int* __restrict__ T, int* __restrict__ bsum,
                      int L0, int L1, int L2, int L3,
                      int nB0, int nB1, int nB2, int nB3) {
    __shared__ int sh[256];
    int blk = blockIdx.x;
    int lb, off, L;
    if (blk < nB0)                  { lb = blk;                 off = 0;            L = L0; }
    else if (blk < nB0 + nB1)       { lb = blk - nB0;           off = L0;           L = L1; }
    else if (blk < nB0 + nB1 + nB2) { lb = blk - nB0 - nB1;     off = L0 + L1;      L = L2; }
    else                            { lb = blk - nB0 - nB1 - nB2; off = L0 + L1 + L2; L = L3; }
    int i = lb * 256 + threadIdx.x;
    int v = (i < L) ? T[off + i] : 0;
    sh[threadIdx.x] = v; __syncthreads();
    for (int o2 = 1; o2 < 256; o2 <<= 1) {
        int tmp = (threadIdx.x >= o2) ? sh[threadIdx.x - o2] : 0;
        __syncthreads();
        sh[threadIdx.x] += tmp; __syncthreads();
    }
    if (i < L) T[off + i] = sh[threadIdx.x] - v;
    if (threadIdx.x == 255) bsum[blk] = sh[255];
}

__global__ void k_st2(int* __restrict__ bsum, int nB0, int nB1, int nB2, int nB3) {
    __shared__ int sh[1024];
    int g = blockIdx.x;
    int off = (g == 0) ? 0 : (g == 1) ? nB0 : (g == 2) ? nB0 + nB1 : nB0 + nB1 + nB2;
    int nb  = (g == 0) ? nB0 : (g == 1) ? nB1 : (g == 2) ? nB2 : nB3;
    int tid = threadIdx.x;
    int v = (tid < nb) ? bsum[off + tid] : 0;
    sh[tid] = v; __syncthreads();
    for (int o2 = 1; o2 < 1024; o2 <<= 1) {
        int t = (tid >= o2) ? sh[tid - o2] : 0;
        __syncthreads();
        sh[tid] += t; __syncthreads();
    }
    if (tid < nb) bsum[off + tid] = sh[tid] - v;
}

__global__ void k_sa2(int* __restrict__ T, const int* __restrict__ bsum,
                      int L0, int L1, int L2, int L3,
                      int nB0, int nB1, int nB2, int nB3) {
    int blk = blockIdx.x;
    int lb, off, L;
    if (blk < nB0)                  { lb = blk;                 off = 0;            L = L0; }
    else if (blk < nB0 + nB1)       { lb = blk - nB0;           off = L0;           L = L1; }
    else if (blk < nB0 + nB1 + nB2) { lb = blk - nB0 - nB1;     off = L0 + L1;      L = L2; }
    else                            { lb = blk - nB0 - nB1 - nB2; off = L0 + L1 + L2; L = L3; }
    int i = lb * 256 + threadIdx.x;
    if (i < L) T[off + i] += bsum[blk];
}

// A2 (no-weight graphs vv/in/ss): register-stage 8 edges/thread, LDS counting
// sort by bin, stream out -> piecewise-contiguous global writes.
__global__ __launch_bounds__(512)
void k_binA2a(const int* __restrict__ vs, const int* __restrict__ vd,
              const int* __restrict__ is_, const int* __restrict__ id_,
              const int* __restrict__ ss_, const int* __restrict__ sd,
              const int* __restrict__ Tv, const int* __restrict__ Ti,
              const int* __restrict__ Ts,
              unsigned* __restrict__ vvbin, unsigned* __restrict__ inbin,
              unsigned* __restrict__ ssbin,
              int ncv, int nci, int ncs, int nbv_, int nbs_,
              int Ev, int Ei, int Es) {
    __shared__ int gbase[512], lscan[512], lcur[512];
    __shared__ unsigned sval[ACH];
    __shared__ int sdst[ACH];
    int blk = blockIdx.x, t = threadIdx.x;
    const int *srcp, *dstp, *T; unsigned* bin; int c, nc, nb, E, sf;
    if (blk < ncv)            { srcp = vs;  dstp = vd;  T = Tv; bin = vvbin; c = blk;             nc = ncv; nb = nbv_; E = Ev; sf = 8; }
    else if (blk < ncv + nci) { srcp = is_; dstp = id_; T = Ti; bin = inbin; c = blk - ncv;       nc = nci; nb = nbs_; E = Ei; sf = 7; }
    else                      { srcp = ss_; dstp = sd;  T = Ts; bin = ssbin; c = blk - ncv - nci; nc = ncs; nb = nbs_; E = Es; sf = 7; }
    int msk = (1 << sf) - 1;
    int p0 = c * ACH, p1 = min(E, p0 + ACH);
    if (t < nb) gbase[t] = T[(size_t)t * nc + c];
    lcur[t] = 0;
    int myS[8], myD[8];
    #pragma unroll
    for (int i = 0; i < 8; i++) {
        int p = p0 + t + i * 512;
        if (p < p1) { myS[i] = srcp[p]; myD[i] = dstp[p]; }
        else myD[i] = -1;
    }
    __syncthreads();
    #pragma unroll
    for (int i = 0; i < 8; i++)
        if (myD[i] >= 0) atomicAdd(&lcur[myD[i] >> sf], 1);
    __syncthreads();
    int v = lcur[t];
    lscan[t] = v;
    __syncthreads();
    for (int off = 1; off < 512; off <<= 1) {
        int tmp = (t >= off) ? lscan[t - off] : 0;
        __syncthreads();
        lscan[t] += tmp;
        __syncthreads();
    }
    int excl = lscan[t] - v;
    __syncthreads();
    lscan[t] = excl;
    lcur[t] = 0;
    __syncthreads();
    #pragma unroll
    for (int i = 0; i < 8; i++) {
        if (myD[i] < 0) continue;
        int b = myD[i] >> sf;
        int r = atomicAdd(&lcur[b], 1);
        int pos = lscan[b] + r;
        sval[pos] = ((unsigned)myS[i] << sf) | (unsigned)(myD[i] & msk);
        sdst[pos] = gbase[b] + r;
    }
    __syncthreads();
    int cntE = p1 - p0;
    for (int q = t; q < cntE; q += 512) bin[sdst[q]] = sval[q];
}

// A2 for the weighted h graph (int2 payload)
__global__ __launch_bounds__(512)
void k_binA2h(const int* __restrict__ hs, const int* __restrict__ hd,
              const float* __restrict__ hw, const int* __restrict__ Th,
              int2* __restrict__ hbin, int nch, int nbs_, int Eh) {
    __shared__ int gbase[512], lscan[512], lcur[512];
    __shared__ unsigned sval[ACH];
    __shared__ int sdst[ACH];
    __shared__ float swt[ACH];
    int c = blockIdx.x, t = threadIdx.x;
    const int sf = 7, msk = 127;
    int p0 = c * ACH, p1 = min(Eh, p0 + ACH);
    if (t < nbs_) gbase[t] = Th[(size_t)t * nch + c];
    lcur[t] = 0;
    int myS[8], myD[8]; float myW[8];
    #pragma unroll
    for (int i = 0; i < 8; i++) {
        int p = p0 + t + i * 512;
        if (p < p1) { myS[i] = hs[p]; myD[i] = hd[p]; myW[i] = hw[p]; }
        else myD[i] = -1;
    }
    __syncthreads();
    #pragma unroll
    for (int i = 0; i < 8; i++)
        if (myD[i] >= 0) atomicAdd(&lcur[myD[i] >> sf], 1);
    __syncthreads();
    int v = lcur[t];
    lscan[t] = v;
    __syncthreads();
    for (int off = 1; off < 512; off <<= 1) {
        int tmp = (t >= off) ? lscan[t - off] : 0;
        __syncthreads();
        lscan[t] += tmp;
        __syncthreads();
    }
    int excl = lscan[t] - v;
    __syncthreads();
    lscan[t] = excl;
    lcur[t] = 0;
    __syncthreads();
    #pragma unroll
    for (int i = 0; i < 8; i++) {
        if (myD[i] < 0) continue;
        int b = myD[i] >> sf;
        int r = atomicAdd(&lcur[b], 1);
        int pos = lscan[b] + r;
        sval[pos] = ((unsigned)myS[i] << sf) | (unsigned)(myD[i] & msk);
        sdst[pos] = gbase[b] + r;
        swt[pos] = myW[i];
    }
    __syncthreads();
    int cntE = p1 - p0;
    for (int q = t; q < cntE; q += 512)
        hbin[sdst[q]] = make_int2((int)sval[q], __float_as_int(swt[q]));
}

__global__ void k_binB(const unsigned* __restrict__ vvbin, const int2* __restrict__ hbin,
                       const unsigned* __restrict__ inbin, const unsigned* __restrict__ ssbin,
                       const int* __restrict__ Tv, const int* __restrict__ Th,
                       const int* __restrict__ Ti, const int* __restrict__ Ts,
                       int* __restrict__ rv, int* __restrict__ rh,
                       int* __restrict__ ri, int* __restrict__ rs,
                       float* __restrict__ dinv_v, float* __restrict__ dinv_s,
                       int* __restrict__ vvsrc, int2* __restrict__ hsw,
                       int* __restrict__ insrc, int* __restrict__ sssrc,
                       int ncv, int nch, int nci, int ncs,
                       int nbv_, int nbs_, int nv, int ns,
                       int Ev, int Eh, int Ei, int Es) {
    __shared__ int cnt[256]; __shared__ int pre[256]; __shared__ int cur[256];
    int blk = blockIdx.x, t = threadIdx.x;
    int g, b, nb, nc, sf, n, E; const int* T; int* rp;
    if (blk < nbv_)                 { g = 0; b = blk;                 nb = nbv_; nc = ncv; sf = 8; n = nv; E = Ev; T = Tv; rp = rv; }
    else if (blk < nbv_ + nbs_)     { g = 1; b = blk - nbv_;          nb = nbs_; nc = nch; sf = 7; n = ns; E = Eh; T = Th; rp = rh; }
    else if (blk < nbv_ + 2 * nbs_) { g = 2; b = blk - nbv_ - nbs_;   nb = nbs_; nc = nci; sf = 7; n = ns; E = Ei; T = Ti; rp = ri; }
    else                            { g = 3; b = blk - nbv_ - 2 * nbs_; nb = nbs_; nc = ncs; sf = 7; n = ns; E = Es; T = Ts; rp = rs; }
    int W = 1 << sf, msk = W - 1;
    int e0 = T[(size_t)b * nc];
    int e1 = (b + 1 < nb) ? T[(size_t)(b + 1) * nc] : E;
    cnt[t] = 0; __syncthreads();
    for (int p = e0 + t; p < e1; p += 256) {
        unsigned pk = (g == 1) ? (unsigned)hbin[p].x
                    : (g == 0) ? vvbin[p] : (g == 2) ? inbin[p] : ssbin[p];
        atomicAdd(&cnt[pk & msk], 1);
    }
    __syncthreads();
    int v = cnt[t];
    pre[t] = v; __syncthreads();
    for (int o2 = 1; o2 < 256; o2 <<= 1) {
        int tmp = (t >= o2) ? pre[t - o2] : 0;
        __syncthreads();
        pre[t] += tmp; __syncthreads();
    }
    int excl = pre[t] - v;
    int d = b * W + t;
    if (t < W && d < n) {
        rp[d] = e0 + excl;
        if (g == 0)      dinv_v[d] = v > 0 ? rsqrtf((float)v) : 0.f;
        else if (g == 3) dinv_s[d] = v > 0 ? rsqrtf((float)v) : 0.f;
    }
    cur[t] = e0 + excl;
    __syncthreads();
    for (int p = e0 + t; p < e1; p += 256) {
        if (g == 1) {
            int2 r = hbin[p];
            unsigned pk = (unsigned)r.x;
            int pos = atomicAdd(&cur[pk & msk], 1);
            hsw[pos] = make_int2((int)(pk >> sf), r.y);
        } else {
            unsigned pk = (g == 0) ? vvbin[p] : (g == 2) ? inbin[p] : ssbin[p];
            int pos = atomicAdd(&cur[pk & msk], 1);
            int sv = (int)(pk >> sf);
            if (g == 0)      vvsrc[pos] = sv;
            else if (g == 2) insrc[pos] = sv;
            else             sssrc[pos] = sv;
        }
    }
    if (b == 0 && t == 0) rp[n] = E;
}

// ================= gathers =================

__global__ void k_gather5(const float* __restrict__ x, const int* __restrict__ rowptr,
                          const int* __restrict__ csr_src, const float* __restrict__ dinv,
                          float* __restrict__ out, int n) {
    int d = blockIdx.x * blockDim.x + threadIdx.x;
    if (d >= n) return;
    int b = rowptr[d], e = rowptr[d + 1];
    float dd = dinv[d];
    float a0 = 0, a1 = 0, a2 = 0, a3 = 0, a4 = 0;
    int p = b;
    for (; p + 4 <= e; p += 4) {
        int s0 = csr_src[p], s1 = csr_src[p+1], s2 = csr_src[p+2], s3 = csr_src[p+3];
        const float* x0 = x + (size_t)s0 * 5;
        const float* x1 = x + (size_t)s1 * 5;
        const float* x2 = x + (size_t)s2 * 5;
        const float* x3 = x + (size_t)s3 * 5;
        float w0 = dd * dinv[s0], w1 = dd * dinv[s1], w2 = dd * dinv[s2], w3 = dd * dinv[s3];
        a0 += x0[0]*w0 + x1[0]*w1 + x2[0]*w2 + x3[0]*w3;
        a1 += x0[1]*w0 + x1[1]*w1 + x2[1]*w2 + x3[1]*w3;
        a2 += x0[2]*w0 + x1[2]*w1 + x2[2]*w2 + x3[2]*w3;
        a3 += x0[3]*w0 + x1[3]*w1 + x2[3]*w2 + x3[3]*w3;
        a4 += x0[4]*w0 + x1[4]*w1 + x2[4]*w2 + x3[4]*w3;
    }
    for (; p < e; p++) {
        int s = csr_src[p];
        float w = dd * dinv[s];
        const float* xp = x + (size_t)s * 5;
        a0 += xp[0]*w; a1 += xp[1]*w; a2 += xp[2]*w; a3 += xp[3]*w; a4 += xp[4]*w;
    }
    float* op = out + (size_t)d * 5;
    op[0] = a0; op[1] = a1; op[2] = a2; op[3] = a3; op[4] = a4;
}

// 64-ch gather over bf16 rows: wave per dst row; 4 groups x 16 lanes x ushort4(8B);
// 4-edge-deep MLP; fp32 accumulate.
// MODE: 0 = plain sum, 1 = per-edge weight (int2 packed), 2 = symmetric gcn norm
// OUTBF: write bf16 row (for next gather hop) vs fp32 row
template<int MODE, bool OUTBF>
__global__ void k_gather64(const unsigned short* __restrict__ xbf, const int* __restrict__ rowptr,
                           const int* __restrict__ csr_src, const int2* __restrict__ csr_sw,
                           const float* __restrict__ dinv, void* __restrict__ outp, int n) {
    int wid = (int)(((long long)blockIdx.x * blockDim.x + threadIdx.x) >> 6);
    if (wid >= n) return;
    int lane = threadIdx.x & 63;
    int g = lane >> 4, q = lane & 15;
    int b = rowptr[wid], e = rowptr[wid + 1];
    float dd = (MODE == 2) ? dinv[wid] : 0.f;
    float4 acc = make_float4(0.f, 0.f, 0.f, 0.f);
    int p = b + g;
    for (; p + 12 < e; p += 16) {
        int s0, s1, s2, s3;
        float w0 = 1.f, w1 = 1.f, w2 = 1.f, w3 = 1.f;
        if (MODE == 1) {
            int2 e0 = csr_sw[p], e1 = csr_sw[p+4], e2 = csr_sw[p+8], e3 = csr_sw[p+12];
            s0 = e0.x; w0 = __int_as_float(e0.y);
            s1 = e1.x; w1 = __int_as_float(e1.y);
            s2 = e2.x; w2 = __int_as_float(e2.y);
            s3 = e3.x; w3 = __int_as_float(e3.y);
        } else {
            s0 = csr_src[p]; s1 = csr_src[p+4]; s2 = csr_src[p+8]; s3 = csr_src[p+12];
            if (MODE == 2) {
                w0 = dd * dinv[s0]; w1 = dd * dinv[s1];
                w2 = dd * dinv[s2]; w3 = dd * dinv[s3];
            }
        }
        ushort4 u0 = ((const ushort4*)(xbf + (size_t)s0 * 64))[q];
        ushort4 u1 = ((const ushort4*)(xbf + (size_t)s1 * 64))[q];
        ushort4 u2 = ((const ushort4*)(xbf + (size_t)s2 * 64))[q];
        ushort4 u3 = ((const ushort4*)(xbf + (size_t)s3 * 64))[q];
        acc.x += bf2f(u0.x)*w0 + bf2f(u1.x)*w1 + bf2f(u2.x)*w2 + bf2f(u3.x)*w3;
        acc.y += bf2f(u0.y)*w0 + bf2f(u1.y)*w1 + bf2f(u2.y)*w2 + bf2f(u3.y)*w3;
        acc.z += bf2f(u0.z)*w0 + bf2f(u1.z)*w1 + bf2f(u2.z)*w2 + bf2f(u3.z)*w3;
        acc.w += bf2f(u0.w)*w0 + bf2f(u1.w)*w1 + bf2f(u2.w)*w2 + bf2f(u3.w)*w3;
    }
    for (; p < e; p += 4) {
        int s; float w = 1.f;
        if (MODE == 1) { int2 e0 = csr_sw[p]; s = e0.x; w = __int_as_float(e0.y); }
        else { s = csr_src[p]; if (MODE == 2) w = dd * dinv[s]; }
        ushort4 u = ((const ushort4*)(xbf + (size_t)s * 64))[q];
        acc.x += bf2f(u.x)*w; acc.y += bf2f(u.y)*w;
        acc.z += bf2f(u.z)*w; acc.w += bf2f(u.w)*w;
    }
    #pragma unroll
    for (int off = 16; off < 64; off <<= 1) {
        acc.x += __shfl_xor(acc.x, off, 64);
        acc.y += __shfl_xor(acc.y, off, 64);
        acc.z += __shfl_xor(acc.z, off, 64);
        acc.w += __shfl_xor(acc.w, off, 64);
    }
    if (g == 0) {
        if (OUTBF) {
            ushort4 ov;
            ov.x = f2bf(acc.x); ov.y = f2bf(acc.y); ov.z = f2bf(acc.z); ov.w = f2bf(acc.w);
            ((ushort4*)outp)[(size_t)wid * 16 + q] = ov;
        } else {
            ((float4*)outp)[(size_t)wid * 16 + q] = acc;
        }
    }
}

// ================= dense combines (wave-tiled register GEMMs) =================

// gx_bf = bf16(relu(b + x@W0 + h1@W1 + h2@W2))
__global__ __launch_bounds__(256, 4)
void k_tag1_w(const float* __restrict__ x, const float* __restrict__ h1,
              const float* __restrict__ h2, const float* __restrict__ W,
              const float* __restrict__ b, unsigned short* __restrict__ out, int n) {
    int wv = (int)(((long long)blockIdx.x * blockDim.x + threadIdx.x) >> 6);
    int lane = threadIdx.x & 63;
    int i0 = wv * 4;
    if (i0 >= n) return;
    float v[4], acc[4];
    #pragma unroll
    for (int r = 0; r < 4; r++) {
        int i = (i0 + r < n) ? i0 + r : n - 1;
        float t = 0.f;
        if (lane < 5)                     t = x [(size_t)i * 5 + lane];
        else if (lane >= 8 && lane < 13)  t = h1[(size_t)i * 5 + lane - 8];
        else if (lane >= 16 && lane < 21) t = h2[(size_t)i * 5 + lane - 16];
        v[r] = t;
        acc[r] = b[lane];
    }
    #pragma unroll
    for (int m = 0; m < 3; m++) {
        #pragma unroll
        for (int k = 0; k < 5; k++) {
            float wk = W[(m * 5 + k) * 64 + lane];
            #pragma unroll
            for (int r = 0; r < 4; r++) acc[r] += bcast(v[r], m * 8 + k) * wk;
        }
    }
    #pragma unroll
    for (int r = 0; r < 4; r++)
        if (i0 + r < n) out[(size_t)(i0 + r) * 64 + lane] = f2bf(fmaxf(acc[r], 0.f));
}

// sx = relu(b + agg@Wrel + state@Wroot)   (fp32 out; only read by dense sage)
__global__ __launch_bounds__(256, 4)
void k_gc_w(const float* __restrict__ agg, const float* __restrict__ st,
            const float* __restrict__ Wrel, const float* __restrict__ Wroot,
            const float* __restrict__ b, float* __restrict__ out, int n) {
    int wv = (int)(((long long)blockIdx.x * blockDim.x + threadIdx.x) >> 6);
    int lane = threadIdx.x & 63;
    int i0 = wv * 4;
    if (i0 >= n) return;
    float xs[4], sr[4], acc[4];
    #pragma unroll
    for (int r = 0; r < 4; r++) {
        int i = (i0 + r < n) ? i0 + r : n - 1;
        xs[r] = agg[(size_t)i * 64 + lane];
        sr[r] = (lane < 6) ? st[(size_t)i * 6 + lane] : 0.f;
        acc[r] = b[lane];
    }
    #pragma unroll 8
    for (int k = 0; k < 64; k++) {
        float wk = Wrel[k * 64 + lane];
        #pragma unroll
        for (int r = 0; r < 4; r++) acc[r] += bcast(xs[r], k) * wk;
    }
    #pragma unroll
    for (int k = 0; k < 6; k++) {
        float wk = Wroot[k * 64 + lane];
        #pragma unroll
        for (int r = 0; r < 4; r++) acc[r] += bcast(sr[r], k) * wk;
    }
    #pragma unroll
    for (int r = 0; r < 4; r++)
        if (i0 + r < n) out[(size_t)(i0 + r) * 64 + lane] = fmaxf(acc[r], 0.f);
}

// sx2_bf = bf16(relu(bl + (ssum/max(cnt,1))@Wl + sx@Wr))
__global__ __launch_bounds__(256, 4)
void k_sage_w(const float* __restrict__ ssum, const int* __restrict__ rp,
              const float* __restrict__ sx, const float* __restrict__ Wl,
              const float* __restrict__ Wr, const float* __restrict__ bl,
              unsigned short* __restrict__ out, int n) {
    int wv = (int)(((long long)blockIdx.x * blockDim.x + threadIdx.x) >> 6);
    int lane = threadIdx.x & 63;
    int i0 = wv * 4;
    if (i0 >= n) return;
    float xs[4], ys[4], acc[4];
    #pragma unroll
    for (int r = 0; r < 4; r++) {
        int i = (i0 + r < n) ? i0 + r : n - 1;
        float cnt = (float)(rp[i + 1] - rp[i]);
        float rs = 1.f / fmaxf(cnt, 1.f);
        xs[r] = ssum[(size_t)i * 64 + lane] * rs;
        ys[r] = sx[(size_t)i * 64 + lane];
        acc[r] = bl[lane];
    }
    #pragma unroll 8
    for (int k = 0; k < 64; k++) {
        float wl = Wl[k * 64 + lane];
        float wr = Wr[k * 64 + lane];
        #pragma unroll
        for (int r = 0; r < 4; r++)
            acc[r] += bcast(xs[r], k) * wl + bcast(ys[r], k) * wr;
    }
    #pragma unroll
    for (int r = 0; r < 4; r++)
        if (i0 + r < n) out[(size_t)(i0 + r) * 64 + lane] = f2bf(fmaxf(acc[r], 0.f));
}

// INIT: out = bias + x@W ; else: out += x@W   (x rows bf16, W 64x64 fp32, out fp32)
template<bool INIT>
__global__ __launch_bounds__(256, 4)
void k_mm_w(const unsigned short* __restrict__ xbf, const float* __restrict__ W,
            const float* __restrict__ bias, float* __restrict__ out, int n) {
    int wv = (int)(((long long)blockIdx.x * blockDim.x + threadIdx.x) >> 6);
    int lane = threadIdx.x & 63;
    int i0 = wv * 4;
    if (i0 >= n) return;
    float xs[4], acc[4];
    #pragma unroll
    for (int r = 0; r < 4; r++) {
        int i = (i0 + r < n) ? i0 + r : n - 1;
        xs[r] = bf2f(xbf[(size_t)i * 64 + lane]);
        acc[r] = INIT ? bias[lane] : out[(size_t)i * 64 + lane];
    }
    #pragma unroll 8
    for (int k = 0; k < 64; k++) {
        float wk = W[k * 64 + lane];
        #pragma unroll
        for (int r = 0; r < 4; r++) acc[r] += bcast(xs[r], k) * wk;
    }
    #pragma unroll
    for (int r = 0; r < 4; r++)
        if (i0 + r < n) out[(size_t)(i0 + r) * 64 + lane] = acc[r];
}

__global__ void k_final(const float* __restrict__ x, const float* __restrict__ W,
                        const float* __restrict__ b, float* __restrict__ out, int n) {
    int t = blockIdx.x * blockDim.x + threadIdx.x;
    if (t >= n * 8) return;
    int i = t >> 3, o = t & 7;
    float acc = b[o];
    #pragma unroll 8
    for (int k = 0; k < 64; k++) acc += fmaxf(x[i * 64 + k], 0.f) * W[k * 8 + o];
    out[t] = acc;
}

static inline unsigned gblk(long long n) { return (unsigned)((n + BLK - 1) / BLK); }
static inline unsigned gwv4(long long n) { return gblk(((n + 3) / 4) * 64); }

extern "C" void kernel_launch(void* const* d_in, const int* in_sizes, int n_in,
                              void* d_out, int out_size, void* d_ws, size_t ws_size,
                              hipStream_t stream) {
    const float* game_x  = (const float*)d_in[0];
    const float* state_x = (const float*)d_in[1];
    const int*   ei_vv   = (const int*)d_in[2];
    const int*   ei_h    = (const int*)d_in[3];
    const float* ea_h    = (const float*)d_in[4];
    const int*   ei_in   = (const int*)d_in[5];
    const int*   ei_ss   = (const int*)d_in[6];
    const float* tag1_W  = (const float*)d_in[7];
    const float* tag1_b  = (const float*)d_in[8];
    const float* tag2_W  = (const float*)d_in[9];
    const float* tag2_b  = (const float*)d_in[10];
    const float* gc_Wrel = (const float*)d_in[11];
    const float* gc_b    = (const float*)d_in[12];
    const float* gc_Wroot= (const float*)d_in[13];
    const float* sage_Wl = (const float*)d_in[14];
    const float* sage_bl = (const float*)d_in[15];
    const float* sage_Wr = (const float*)d_in[16];
    const float* lin_W   = (const float*)d_in[17];
    const float* lin_b   = (const float*)d_in[18];

    const int NV  = in_sizes[0] / 5;
    const int NS  = in_sizes[1] / 6;
    const int EVV = in_sizes[2] / 2;
    const int EH  = in_sizes[3] / 2;
    const int EIN = in_sizes[5] / 2;
    const int ESS = in_sizes[6] / 2;

    const int *vv_s = ei_vv,  *vv_d = ei_vv + EVV;
    const int *h_s  = ei_h,   *h_d  = ei_h  + EH;
    const int *in_s = ei_in,  *in_d = ei_in + EIN;
    const int *ss_s = ei_ss,  *ss_d = ei_ss + ESS;

    // bin geometry
    const int ncv = (EVV + ACH - 1) / ACH;
    const int nch = (EH  + ACH - 1) / ACH;
    const int nci = (EIN + ACH - 1) / ACH;
    const int ncs = (ESS + ACH - 1) / ACH;
    const int nbv_ = (NV + 255) >> 8;   // bin width 256 over NV dsts
    const int nbs_ = (NS + 127) >> 7;   // bin width 128 over NS dsts
    const int Lv = nbv_ * ncv, Lh = nbs_ * nch, Li = nbs_ * nci, Ls = nbs_ * ncs;
    const int nB0 = (Lv + 255) / 256, nB1 = (Lh + 255) / 256,
              nB2 = (Li + 255) / 256, nB3 = (Ls + 255) / 256;

    // ---------------- workspace layout (4-byte words) ----------------
    float* wsf = (float*)d_ws;
    size_t o = 0;
    unsigned short* gx_bf = (unsigned short*)(wsf + o);   // NV x 64 bf16
    float* sx3 = wsf + o; o += (size_t)NV * 32;           // alias (NS*64 fp32 == NV*32 words)
    float* B1 = wsf + o; o += (size_t)NS * 64;            // binned vv|in|ss (phase0) | agg | ssum | hA_bf
    float* B2 = wsf + o; o += (size_t)NS * 64;            // binned h (phase0) | sx | hB_bf
    float* B4 = wsf + o; o += (size_t)NS * 32;            // h1v+h2v (NV*10) | sx2_bf (NS*32)
    int*  vvsrc = (int*)(wsf + o); o += (size_t)EVV;
    int*  sssrc = (int*)(wsf + o); o += (size_t)ESS;
    int*  insrc = (int*)(wsf + o); o += (size_t)EIN;
    int2* hsw   = (int2*)(wsf + o); o += (size_t)EH * 2;
    int* T_all = (int*)(wsf + o); o += (size_t)(Lv + Lh + Li + Ls);
    int* bsum  = (int*)(wsf + o); o += 2048;              // scan block sums
    int* rv = (int*)(wsf + o); o += (size_t)NV + 1;
    int* rh = (int*)(wsf + o); o += (size_t)NS + 1;
    int* ri = (int*)(wsf + o); o += (size_t)NS + 1;
    int* rs = (int*)(wsf + o); o += (size_t)NS + 1;
    float* dinv_v = wsf + o; o += (size_t)NV;
    float* dinv_s = wsf + o; o += (size_t)NS;

    int* Tv = T_all;
    int* Th = Tv + Lv;
    int* Ti = Th + Lh;
    int* Ts = Ti + Li;

    // phase-0 binned edge buffers alias B1/B2 (dead until stage B):
    // B1 holds vv(EVV) + in(EIN) + ss(ESS) u32 = 2.5M <= NS*64 = 3.2M words
    // B2 holds h (EH int2) = 2M words <= 3.2M
    unsigned* vvbin = (unsigned*)B1;
    unsigned* inbin = vvbin + EVV;
    unsigned* ssbin = inbin + EIN;
    int2* hbin = (int2*)B2;

    unsigned short* hA_bf  = (unsigned short*)B1;
    unsigned short* hB_bf  = (unsigned short*)B2;
    unsigned short* sx2_bf = (unsigned short*)B4;

    // ================= Phase 0: atomic-free batched CSR build =================
    int nchunks = ncv + nch + nci + ncs;
    int nbins   = nbv_ + 3 * nbs_;
    int nBtot   = nB0 + nB1 + nB2 + nB3;
    k_binA1<<<nchunks, 256, 0, stream>>>(vv_d, h_d, in_d, ss_d, Tv, Th, Ti, Ts,
                                         ncv, nch, nci, ncs, nbv_, nbs_,
                                         EVV, EH, EIN, ESS);
    k_sb2<<<nBtot, 256, 0, stream>>>(T_all, bsum, Lv, Lh, Li, Ls, nB0, nB1, nB2, nB3);
    k_st2<<<4, 1024, 0, stream>>>(bsum, nB0, nB1, nB2, nB3);
    k_sa2<<<nBtot, 256, 0, stream>>>(T_all, bsum, Lv, Lh, Li, Ls, nB0, nB1, nB2, nB3);
    k_binA2a<<<ncv + nci + ncs, 512, 0, stream>>>(vv_s, vv_d, in_s, in_d, ss_s, ss_d,
                                                  Tv, Ti, Ts, vvbin, inbin, ssbin,
                                                  ncv, nci, ncs, nbv_, nbs_,
                                                  EVV, EIN, ESS);
    k_binA2h<<<nch, 512, 0, stream>>>(h_s, h_d, ea_h, Th, hbin, nch, nbs_, EH);
    k_binB<<<nbins, 256, 0, stream>>>(vvbin, hbin, inbin, ssbin,
                                      Tv, Th, Ti, Ts,
                                      rv, rh, ri, rs, dinv_v, dinv_s,
                                      vvsrc, hsw, insrc, sssrc,
                                      ncv, nch, nci, ncs, nbv_, nbs_,
                                      NV, NS, EVV, EH, EIN, ESS);

    // ================= Stage A: TAGConv1 on v-v =================
    float* h1v = B4;
    float* h2v = B4 + (size_t)NV * 5;
    k_gather5<<<gblk(NV), BLK, 0, stream>>>(game_x, rv, vvsrc, dinv_v, h1v, NV);
    k_gather5<<<gblk(NV), BLK, 0, stream>>>(h1v,    rv, vvsrc, dinv_v, h2v, NV);
    k_tag1_w<<<gwv4(NV), BLK, 0, stream>>>(game_x, h1v, h2v, tag1_W, tag1_b, gx_bf, NV);

    // ================= Stage B: GraphConv (weighted) =================
    k_gather64<1, false><<<gblk((long long)NS * 64), BLK, 0, stream>>>(gx_bf, rh, nullptr, hsw, nullptr, B1, NS);
    k_gc_w<<<gwv4(NS), BLK, 0, stream>>>(B1, state_x, gc_Wrel, gc_Wroot, gc_b, B2, NS);

    // ================= Stage C: SAGE mean =================
    k_gather64<0, false><<<gblk((long long)NS * 64), BLK, 0, stream>>>(gx_bf, ri, insrc, nullptr, nullptr, B1, NS);
    k_sage_w<<<gwv4(NS), BLK, 0, stream>>>(B1, ri, B2, sage_Wl, sage_Wr, sage_bl, sx2_bf, NS);

    // ================= Stage D: TAGConv2 on s-s (K=3) =================
    // gx_bf dead -> sx3 alias; B1 (ssum) dead -> hA_bf; B2 (sx) dead -> hB_bf
    k_mm_w<true><<<gwv4(NS), BLK, 0, stream>>>(sx2_bf, tag2_W, tag2_b, sx3, NS);
    k_gather64<2, true><<<gblk((long long)NS * 64), BLK, 0, stream>>>(sx2_bf, rs, sssrc, nullptr, dinv_s, hA_bf, NS);
    k_mm_w<false><<<gwv4(NS), BLK, 0, stream>>>(hA_bf, tag2_W + 4096, nullptr, sx3, NS);
    k_gather64<2, true><<<gblk((long long)NS * 64), BLK, 0, stream>>>(hA_bf, rs, sssrc, nullptr, dinv_s, hB_bf, NS);
    k_mm_w<false><<<gwv4(NS), BLK, 0, stream>>>(hB_bf, tag2_W + 8192, nullptr, sx3, NS);
    k_gather64<2, true><<<gblk((long long)NS * 64), BLK, 0, stream>>>(hB_bf, rs, sssrc, nullptr, dinv_s, hA_bf, NS);
    k_mm_w<false><<<gwv4(NS), BLK, 0, stream>>>(hA_bf, tag2_W + 12288, nullptr, sx3, NS);

    // ================= Stage E: final linear (relu fused) =================
    k_final<<<gblk((long long)NS * 8), BLK, 0, stream>>>(sx3, lin_W, lin_b, (float*)d_out, NS);
}

// Round 4
// 433.634 us; speedup vs baseline: 1.5111x; 1.1512x over previous
//
#include <hip/hip_runtime.h>

#define BLK 256
#define ACH 4096   // edges per block in bin passes

// broadcast lane l of v across the wave (l wave-uniform; dynamic is legal)
__device__ __forceinline__ float bcast(float v, int l) {
    return __int_as_float(__builtin_amdgcn_readlane(__float_as_int(v), l));
}
// fp32 <-> bf16 (round-to-nearest-even)
__device__ __forceinline__ unsigned short f2bf(float f) {
    unsigned u = __float_as_uint(f);
    return (unsigned short)((u + 0x7FFFu + ((u >> 16) & 1u)) >> 16);
}
__device__ __forceinline__ float bf2f(unsigned short b) {
    return __uint_as_float(((unsigned)b) << 16);
}

// ---------------- MFMA fragment types (per guide §3: short8 == 8 bf16) ------
typedef __attribute__((ext_vector_type(8))) short bf16x8;
typedef __attribute__((ext_vector_type(4))) float f32x4;

// split 8 fp32 (scaled) into hi/lo bf16 fragments: v ~= hi + lo, |lo|<=2^-9|v|
__device__ __forceinline__ void split8s(const float* p, float s, bf16x8& h, bf16x8& l) {
    #pragma unroll
    for (int j = 0; j < 8; j++) {
        float v = p[j] * s;
        unsigned short hb = f2bf(v);
        h[j] = (short)hb;
        l[j] = (short)f2bf(v - bf2f(hb));
    }
}
// gather W[kbase+j][col] (stride-64 fp32), split hi/lo
__device__ __forceinline__ void loadWsplit(const float* W, int kbase, int col,
                                           bf16x8& h, bf16x8& l) {
    #pragma unroll
    for (int j = 0; j < 8; j++) {
        float v = W[(size_t)(kbase + j) * 64 + col];
        unsigned short hb = f2bf(v);
        h[j] = (short)hb;
        l[j] = (short)f2bf(v - bf2f(hb));
    }
}

// ================= atomic-free CSR build (two-level binned counting sort) ====

__global__ void k_binA1(const int* __restrict__ vd, const int* __restrict__ hd,
                        const int* __restrict__ id_, const int* __restrict__ sd,
                        int* __restrict__ Tv, int* __restrict__ Th,
                        int* __restrict__ Ti, int* __restrict__ Ts,
                        int ncv, int nch, int nci, int ncs,
                        int nbv_, int nbs_, int Ev, int Eh, int Ei, int Es) {
    __shared__ int cnt[512];
    int blk = blockIdx.x, t = threadIdx.x;
    const int* dd; int* T; int c, nc, nb, E, sf;
    if (blk < ncv)                 { dd = vd;  T = Tv; c = blk;               nc = ncv; nb = nbv_; E = Ev; sf = 8; }
    else if (blk < ncv + nch)      { dd = hd;  T = Th; c = blk - ncv;         nc = nch; nb = nbs_; E = Eh; sf = 7; }
    else if (blk < ncv + nch + nci){ dd = id_; T = Ti; c = blk - ncv - nch;   nc = nci; nb = nbs_; E = Ei; sf = 7; }
    else                           { dd = sd;  T = Ts; c = blk - ncv - nch - nci; nc = ncs; nb = nbs_; E = Es; sf = 7; }
    cnt[t] = 0; cnt[t + 256] = 0;
    __syncthreads();
    int p0 = c * ACH, p1 = min(E, p0 + ACH);
    for (int p = p0 + t; p < p1; p += 256) atomicAdd(&cnt[dd[p] >> sf], 1);
    __syncthreads();
    for (int b = t; b < nb; b += 256) T[(size_t)b * nc + c] = cnt[b];
}

// 3-level exclusive scan over the 4 concatenated T arrays (in place)
__global__ void k_sb2(int* __restrict__ T, int* __restrict__ bsum,
                      int L0, int L1, int L2, int L3,
                      int nB0, int nB1, int nB2, int nB3) {
    __shared__ int sh[256];
    int blk = blockIdx.x;
    int lb, off, L;
    if (blk < nB0)                  { lb = blk;                 off = 0;            L = L0; }
    else if (blk < nB0 + nB1)       { lb = blk - nB0;           off = L0;           L = L1; }
    else if (blk < nB0 + nB1 + nB2) { lb = blk - nB0 - nB1;     off = L0 + L1;      L = L2; }
    else                            { lb = blk - nB0 - nB1 - nB2; off = L0 + L1 + L2; L = L3; }
    int i = lb * 256 + threadIdx.x;
    int v = (i < L) ? T[off + i] : 0;
    sh[threadIdx.x] = v; __syncthreads();
    for (int o2 = 1; o2 < 256; o2 <<= 1) {
        int tmp = (threadIdx.x >= o2) ? sh[threadIdx.x - o2] : 0;
        __syncthreads();
        sh[threadIdx.x] += tmp; __syncthreads();
    }
    if (i < L) T[off + i] = sh[threadIdx.x] - v;
    if (threadIdx.x == 255) bsum[blk] = sh[255];
}

__global__ void k_st2(int* __restrict__ bsum, int nB0, int nB1, int nB2, int nB3) {
    __shared__ int sh[1024];
    int g = blockIdx.x;
    int off = (g == 0) ? 0 : (g == 1) ? nB0 : (g == 2) ? nB0 + nB1 : nB0 + nB1 + nB2;
    int nb  = (g == 0) ? nB0 : (g == 1) ? nB1 : (g == 2) ? nB2 : nB3;
    int tid = threadIdx.x;
    int v = (tid < nb) ? bsum[off + tid] : 0;
    sh[tid] = v; __syncthreads();
    for (int o2 = 1; o2 < 1024; o2 <<= 1) {
        int t = (tid >= o2) ? sh[tid - o2] : 0;
        __syncthreads();
        sh[tid] += t; __syncthreads();
    }
    if (tid < nb) bsum[off + tid] = sh[tid] - v;
}

__global__ void k_sa2(int* __restrict__ T, const int* __restrict__ bsum,
                      int L0, int L1, int L2, int L3,
                      int nB0, int nB1, int nB2, int nB3) {
    int blk = blockIdx.x;
    int lb, off, L;
    if (blk < nB0)                  { lb = blk;                 off = 0;            L = L0; }
    else if (blk < nB0 + nB1)       { lb = blk - nB0;           off = L0;           L = L1; }
    else if (blk < nB0 + nB1 + nB2) { lb = blk - nB0 - nB1;     off = L0 + L1;      L = L2; }
    else                            { lb = blk - nB0 - nB1 - nB2; off = L0 + L1 + L2; L = L3; }
    int i = lb * 256 + threadIdx.x;
    if (i < L) T[off + i] += bsum[blk];
}

// A2 (no-weight graphs vv/in/ss): register-stage 8 edges/thread, LDS counting
// sort by bin, stream out -> piecewise-contiguous global writes.
__global__ __launch_bounds__(512)
void k_binA2a(const int* __restrict__ vs, const int* __restrict__ vd,
              const int* __restrict__ is_, const int* __restrict__ id_,
              const int* __restrict__ ss_, const int* __restrict__ sd,
              const int* __restrict__ Tv, const int* __restrict__ Ti,
              const int* __restrict__ Ts,
              unsigned* __restrict__ vvbin, unsigned* __restrict__ inbin,
              unsigned* __restrict__ ssbin,
              int ncv, int nci, int ncs, int nbv_, int nbs_,
              int Ev, int Ei, int Es) {
    __shared__ int gbase[512], lscan[512], lcur[512];
    __shared__ unsigned sval[ACH];
    __shared__ int sdst[ACH];
    int blk = blockIdx.x, t = threadIdx.x;
    const int *srcp, *dstp, *T; unsigned* bin; int c, nc, nb, E, sf;
    if (blk < ncv)            { srcp = vs;  dstp = vd;  T = Tv; bin = vvbin; c = blk;             nc = ncv; nb = nbv_; E = Ev; sf = 8; }
    else if (blk < ncv + nci) { srcp = is_; dstp = id_; T = Ti; bin = inbin; c = blk - ncv;       nc = nci; nb = nbs_; E = Ei; sf = 7; }
    else                      { srcp = ss_; dstp = sd;  T = Ts; bin = ssbin; c = blk - ncv - nci; nc = ncs; nb = nbs_; E = Es; sf = 7; }
    int msk = (1 << sf) - 1;
    int p0 = c * ACH, p1 = min(E, p0 + ACH);
    if (t < nb) gbase[t] = T[(size_t)t * nc + c];
    lcur[t] = 0;
    int myS[8], myD[8];
    #pragma unroll
    for (int i = 0; i < 8; i++) {
        int p = p0 + t + i * 512;
        if (p < p1) { myS[i] = srcp[p]; myD[i] = dstp[p]; }
        else myD[i] = -1;
    }
    __syncthreads();
    #pragma unroll
    for (int i = 0; i < 8; i++)
        if (myD[i] >= 0) atomicAdd(&lcur[myD[i] >> sf], 1);
    __syncthreads();
    int v = lcur[t];
    lscan[t] = v;
    __syncthreads();
    for (int off = 1; off < 512; off <<= 1) {
        int tmp = (t >= off) ? lscan[t - off] : 0;
        __syncthreads();
        lscan[t] += tmp;
        __syncthreads();
    }
    int excl = lscan[t] - v;
    __syncthreads();
    lscan[t] = excl;
    lcur[t] = 0;
    __syncthreads();
    #pragma unroll
    for (int i = 0; i < 8; i++) {
        if (myD[i] < 0) continue;
        int b = myD[i] >> sf;
        int r = atomicAdd(&lcur[b], 1);
        int pos = lscan[b] + r;
        sval[pos] = ((unsigned)myS[i] << sf) | (unsigned)(myD[i] & msk);
        sdst[pos] = gbase[b] + r;
    }
    __syncthreads();
    int cntE = p1 - p0;
    for (int q = t; q < cntE; q += 512) bin[sdst[q]] = sval[q];
}

// A2 for the weighted h graph (int2 payload)
__global__ __launch_bounds__(512)
void k_binA2h(const int* __restrict__ hs, const int* __restrict__ hd,
              const float* __restrict__ hw, const int* __restrict__ Th,
              int2* __restrict__ hbin, int nch, int nbs_, int Eh) {
    __shared__ int gbase[512], lscan[512], lcur[512];
    __shared__ unsigned sval[ACH];
    __shared__ int sdst[ACH];
    __shared__ float swt[ACH];
    int c = blockIdx.x, t = threadIdx.x;
    const int sf = 7, msk = 127;
    int p0 = c * ACH, p1 = min(Eh, p0 + ACH);
    if (t < nbs_) gbase[t] = Th[(size_t)t * nch + c];
    lcur[t] = 0;
    int myS[8], myD[8]; float myW[8];
    #pragma unroll
    for (int i = 0; i < 8; i++) {
        int p = p0 + t + i * 512;
        if (p < p1) { myS[i] = hs[p]; myD[i] = hd[p]; myW[i] = hw[p]; }
        else myD[i] = -1;
    }
    __syncthreads();
    #pragma unroll
    for (int i = 0; i < 8; i++)
        if (myD[i] >= 0) atomicAdd(&lcur[myD[i] >> sf], 1);
    __syncthreads();
    int v = lcur[t];
    lscan[t] = v;
    __syncthreads();
    for (int off = 1; off < 512; off <<= 1) {
        int tmp = (t >= off) ? lscan[t - off] : 0;
        __syncthreads();
        lscan[t] += tmp;
        __syncthreads();
    }
    int excl = lscan[t] - v;
    __syncthreads();
    lscan[t] = excl;
    lcur[t] = 0;
    __syncthreads();
    #pragma unroll
    for (int i = 0; i < 8; i++) {
        if (myD[i] < 0) continue;
        int b = myD[i] >> sf;
        int r = atomicAdd(&lcur[b], 1);
        int pos = lscan[b] + r;
        sval[pos] = ((unsigned)myS[i] << sf) | (unsigned)(myD[i] & msk);
        sdst[pos] = gbase[b] + r;
        swt[pos] = myW[i];
    }
    __syncthreads();
    int cntE = p1 - p0;
    for (int q = t; q < cntE; q += 512)
        hbin[sdst[q]] = make_int2((int)sval[q], __float_as_int(swt[q]));
}

__global__ void k_binB(const unsigned* __restrict__ vvbin, const int2* __restrict__ hbin,
                       const unsigned* __restrict__ inbin, const unsigned* __restrict__ ssbin,
                       const int* __restrict__ Tv, const int* __restrict__ Th,
                       const int* __restrict__ Ti, const int* __restrict__ Ts,
                       int* __restrict__ rv, int* __restrict__ rh,
                       int* __restrict__ ri, int* __restrict__ rs,
                       float* __restrict__ dinv_v, float* __restrict__ dinv_s,
                       int* __restrict__ vvsrc, int2* __restrict__ hsw,
                       int* __restrict__ insrc, int* __restrict__ sssrc,
                       int ncv, int nch, int nci, int ncs,
                       int nbv_, int nbs_, int nv, int ns,
                       int Ev, int Eh, int Ei, int Es) {
    __shared__ int cnt[256]; __shared__ int pre[256]; __shared__ int cur[256];
    int blk = blockIdx.x, t = threadIdx.x;
    int g, b, nb, nc, sf, n, E; const int* T; int* rp;
    if (blk < nbv_)                 { g = 0; b = blk;                 nb = nbv_; nc = ncv; sf = 8; n = nv; E = Ev; T = Tv; rp = rv; }
    else if (blk < nbv_ + nbs_)     { g = 1; b = blk - nbv_;          nb = nbs_; nc = nch; sf = 7; n = ns; E = Eh; T = Th; rp = rh; }
    else if (blk < nbv_ + 2 * nbs_) { g = 2; b = blk - nbv_ - nbs_;   nb = nbs_; nc = nci; sf = 7; n = ns; E = Ei; T = Ti; rp = ri; }
    else                            { g = 3; b = blk - nbv_ - 2 * nbs_; nb = nbs_; nc = ncs; sf = 7; n = ns; E = Es; T = Ts; rp = rs; }
    int W = 1 << sf, msk = W - 1;
    int e0 = T[(size_t)b * nc];
    int e1 = (b + 1 < nb) ? T[(size_t)(b + 1) * nc] : E;
    cnt[t] = 0; __syncthreads();
    for (int p = e0 + t; p < e1; p += 256) {
        unsigned pk = (g == 1) ? (unsigned)hbin[p].x
                    : (g == 0) ? vvbin[p] : (g == 2) ? inbin[p] : ssbin[p];
        atomicAdd(&cnt[pk & msk], 1);
    }
    __syncthreads();
    int v = cnt[t];
    pre[t] = v; __syncthreads();
    for (int o2 = 1; o2 < 256; o2 <<= 1) {
        int tmp = (t >= o2) ? pre[t - o2] : 0;
        __syncthreads();
        pre[t] += tmp; __syncthreads();
    }
    int excl = pre[t] - v;
    int d = b * W + t;
    if (t < W && d < n) {
        rp[d] = e0 + excl;
        if (g == 0)      dinv_v[d] = v > 0 ? rsqrtf((float)v) : 0.f;
        else if (g == 3) dinv_s[d] = v > 0 ? rsqrtf((float)v) : 0.f;
    }
    cur[t] = e0 + excl;
    __syncthreads();
    for (int p = e0 + t; p < e1; p += 256) {
        if (g == 1) {
            int2 r = hbin[p];
            unsigned pk = (unsigned)r.x;
            int pos = atomicAdd(&cur[pk & msk], 1);
            hsw[pos] = make_int2((int)(pk >> sf), r.y);
        } else {
            unsigned pk = (g == 0) ? vvbin[p] : (g == 2) ? inbin[p] : ssbin[p];
            int pos = atomicAdd(&cur[pk & msk], 1);
            int sv = (int)(pk >> sf);
            if (g == 0)      vvsrc[pos] = sv;
            else if (g == 2) insrc[pos] = sv;
            else             sssrc[pos] = sv;
        }
    }
    if (b == 0 && t == 0) rp[n] = E;
}

// ================= gathers =================

__global__ void k_gather5(const float* __restrict__ x, const int* __restrict__ rowptr,
                          const int* __restrict__ csr_src, const float* __restrict__ dinv,
                          float* __restrict__ out, int n) {
    int d = blockIdx.x * blockDim.x + threadIdx.x;
    if (d >= n) return;
    int b = rowptr[d], e = rowptr[d + 1];
    float dd = dinv[d];
    float a0 = 0, a1 = 0, a2 = 0, a3 = 0, a4 = 0;
    int p = b;
    for (; p + 4 <= e; p += 4) {
        int s0 = csr_src[p], s1 = csr_src[p+1], s2 = csr_src[p+2], s3 = csr_src[p+3];
        const float* x0 = x + (size_t)s0 * 5;
        const float* x1 = x + (size_t)s1 * 5;
        const float* x2 = x + (size_t)s2 * 5;
        const float* x3 = x + (size_t)s3 * 5;
        float w0 = dd * dinv[s0], w1 = dd * dinv[s1], w2 = dd * dinv[s2], w3 = dd * dinv[s3];
        a0 += x0[0]*w0 + x1[0]*w1 + x2[0]*w2 + x3[0]*w3;
        a1 += x0[1]*w0 + x1[1]*w1 + x2[1]*w2 + x3[1]*w3;
        a2 += x0[2]*w0 + x1[2]*w1 + x2[2]*w2 + x3[2]*w3;
        a3 += x0[3]*w0 + x1[3]*w1 + x2[3]*w2 + x3[3]*w3;
        a4 += x0[4]*w0 + x1[4]*w1 + x2[4]*w2 + x3[4]*w3;
    }
    for (; p < e; p++) {
        int s = csr_src[p];
        float w = dd * dinv[s];
        const float* xp = x + (size_t)s * 5;
        a0 += xp[0]*w; a1 += xp[1]*w; a2 += xp[2]*w; a3 += xp[3]*w; a4 += xp[4]*w;
    }
    float* op = out + (size_t)d * 5;
    op[0] = a0; op[1] = a1; op[2] = a2; op[3] = a3; op[4] = a4;
}

// 64-ch gather over bf16 rows: wave per dst row; 4 groups x 16 lanes x ushort4(8B);
// 4-edge-deep MLP; fp32 accumulate.
// MODE: 0 = plain sum, 1 = per-edge weight (int2 packed), 2 = symmetric gcn norm
// OUTBF: write bf16 row (for next gather hop) vs fp32 row
template<int MODE, bool OUTBF>
__global__ void k_gather64(const unsigned short* __restrict__ xbf, const int* __restrict__ rowptr,
                           const int* __restrict__ csr_src, const int2* __restrict__ csr_sw,
                           const float* __restrict__ dinv, void* __restrict__ outp, int n) {
    int wid = (int)(((long long)blockIdx.x * blockDim.x + threadIdx.x) >> 6);
    if (wid >= n) return;
    int lane = threadIdx.x & 63;
    int g = lane >> 4, q = lane & 15;
    int b = rowptr[wid], e = rowptr[wid + 1];
    float dd = (MODE == 2) ? dinv[wid] : 0.f;
    float4 acc = make_float4(0.f, 0.f, 0.f, 0.f);
    int p = b + g;
    for (; p + 12 < e; p += 16) {
        int s0, s1, s2, s3;
        float w0 = 1.f, w1 = 1.f, w2 = 1.f, w3 = 1.f;
        if (MODE == 1) {
            int2 e0 = csr_sw[p], e1 = csr_sw[p+4], e2 = csr_sw[p+8], e3 = csr_sw[p+12];
            s0 = e0.x; w0 = __int_as_float(e0.y);
            s1 = e1.x; w1 = __int_as_float(e1.y);
            s2 = e2.x; w2 = __int_as_float(e2.y);
            s3 = e3.x; w3 = __int_as_float(e3.y);
        } else {
            s0 = csr_src[p]; s1 = csr_src[p+4]; s2 = csr_src[p+8]; s3 = csr_src[p+12];
            if (MODE == 2) {
                w0 = dd * dinv[s0]; w1 = dd * dinv[s1];
                w2 = dd * dinv[s2]; w3 = dd * dinv[s3];
            }
        }
        ushort4 u0 = ((const ushort4*)(xbf + (size_t)s0 * 64))[q];
        ushort4 u1 = ((const ushort4*)(xbf + (size_t)s1 * 64))[q];
        ushort4 u2 = ((const ushort4*)(xbf + (size_t)s2 * 64))[q];
        ushort4 u3 = ((const ushort4*)(xbf + (size_t)s3 * 64))[q];
        acc.x += bf2f(u0.x)*w0 + bf2f(u1.x)*w1 + bf2f(u2.x)*w2 + bf2f(u3.x)*w3;
        acc.y += bf2f(u0.y)*w0 + bf2f(u1.y)*w1 + bf2f(u2.y)*w2 + bf2f(u3.y)*w3;
        acc.z += bf2f(u0.z)*w0 + bf2f(u1.z)*w1 + bf2f(u2.z)*w2 + bf2f(u3.z)*w3;
        acc.w += bf2f(u0.w)*w0 + bf2f(u1.w)*w1 + bf2f(u2.w)*w2 + bf2f(u3.w)*w3;
    }
    for (; p < e; p += 4) {
        int s; float w = 1.f;
        if (MODE == 1) { int2 e0 = csr_sw[p]; s = e0.x; w = __int_as_float(e0.y); }
        else { s = csr_src[p]; if (MODE == 2) w = dd * dinv[s]; }
        ushort4 u = ((const ushort4*)(xbf + (size_t)s * 64))[q];
        acc.x += bf2f(u.x)*w; acc.y += bf2f(u.y)*w;
        acc.z += bf2f(u.z)*w; acc.w += bf2f(u.w)*w;
    }
    #pragma unroll
    for (int off = 16; off < 64; off <<= 1) {
        acc.x += __shfl_xor(acc.x, off, 64);
        acc.y += __shfl_xor(acc.y, off, 64);
        acc.z += __shfl_xor(acc.z, off, 64);
        acc.w += __shfl_xor(acc.w, off, 64);
    }
    if (g == 0) {
        if (OUTBF) {
            ushort4 ov;
            ov.x = f2bf(acc.x); ov.y = f2bf(acc.y); ov.z = f2bf(acc.z); ov.w = f2bf(acc.w);
            ((ushort4*)outp)[(size_t)wid * 16 + q] = ov;
        } else {
            ((float4*)outp)[(size_t)wid * 16 + q] = acc;
        }
    }
}

// ============ dense combines (MFMA wave GEMMs, 32 rows x 64 cols/wave) =======
// k-map: A and B both loaded with k = kh*32 + g*8 + j (g = lane>>4, j = elem).
// Any shared bijection is correct since HW pairs identical (g,j) for A and B.
// C/D layout (HW-verified): col = lane&15, row = g*4 + reg.
// W is fp32 -> hi/lo bf16 split; fp32 X -> hi/lo split (3-term product);
// bf16 X is exact in one term.

// out = (INIT? bias : out) + xbf @ W
template<bool INIT>
__global__ __launch_bounds__(256)
void k_mm_mf(const unsigned short* __restrict__ xbf, const float* __restrict__ W,
             const float* __restrict__ bias, float* __restrict__ out, int n) {
    int wv = (int)(((long long)blockIdx.x * blockDim.x + threadIdx.x) >> 6);
    int lane = threadIdx.x & 63;
    int r0 = wv * 32;
    if (r0 >= n) return;
    int lm = lane & 15, g = lane >> 4;
    bf16x8 a[2][2];
    #pragma unroll
    for (int mt = 0; mt < 2; mt++) {
        int row = r0 + mt * 16 + lm; if (row >= n) row = n - 1;
        #pragma unroll
        for (int kh = 0; kh < 2; kh++)
            a[mt][kh] = *(const bf16x8*)(xbf + (size_t)row * 64 + kh * 32 + g * 8);
    }
    #pragma unroll
    for (int nt = 0; nt < 4; nt++) {
        int col = nt * 16 + lm;
        bf16x8 bh[2], blo[2];
        #pragma unroll
        for (int kh = 0; kh < 2; kh++) loadWsplit(W, kh * 32 + g * 8, col, bh[kh], blo[kh]);
        #pragma unroll
        for (int mt = 0; mt < 2; mt++) {
            f32x4 acc = {0.f, 0.f, 0.f, 0.f};
            #pragma unroll
            for (int kh = 0; kh < 2; kh++) {
                acc = __builtin_amdgcn_mfma_f32_16x16x32_bf16(a[mt][kh], bh[kh],  acc, 0, 0, 0);
                acc = __builtin_amdgcn_mfma_f32_16x16x32_bf16(a[mt][kh], blo[kh], acc, 0, 0, 0);
            }
            #pragma unroll
            for (int r = 0; r < 4; r++) {
                int row = r0 + mt * 16 + g * 4 + r;
                if (row < n) {
                    float base = INIT ? bias[col] : out[(size_t)row * 64 + col];
                    out[(size_t)row * 64 + col] = base + acc[r];
                }
            }
        }
    }
}

// sx2_bf = bf16(relu(bl + (ssum/max(cnt,1))@Wl + sx@Wr))
__global__ __launch_bounds__(256)
void k_sage_mf(const float* __restrict__ ssum, const int* __restrict__ rp,
               const float* __restrict__ sx, const float* __restrict__ Wl,
               const float* __restrict__ Wr, const float* __restrict__ bl,
               unsigned short* __restrict__ out, int n) {
    int wv = (int)(((long long)blockIdx.x * blockDim.x + threadIdx.x) >> 6);
    int lane = threadIdx.x & 63;
    int r0 = wv * 32;
    if (r0 >= n) return;
    int lm = lane & 15, g = lane >> 4;
    bf16x8 axh[2][2], axl[2][2], ayh[2][2], ayl[2][2];
    #pragma unroll
    for (int mt = 0; mt < 2; mt++) {
        int row = r0 + mt * 16 + lm; if (row >= n) row = n - 1;
        float cnt = (float)(rp[row + 1] - rp[row]);
        float rs = 1.f / fmaxf(cnt, 1.f);
        #pragma unroll
        for (int kh = 0; kh < 2; kh++) {
            split8s(ssum + (size_t)row * 64 + kh * 32 + g * 8, rs,  axh[mt][kh], axl[mt][kh]);
            split8s(sx   + (size_t)row * 64 + kh * 32 + g * 8, 1.f, ayh[mt][kh], ayl[mt][kh]);
        }
    }
    #pragma unroll
    for (int nt = 0; nt < 4; nt++) {
        int col = nt * 16 + lm;
        bf16x8 blh[2], bll[2], brh[2], brl[2];
        #pragma unroll
        for (int kh = 0; kh < 2; kh++) {
            loadWsplit(Wl, kh * 32 + g * 8, col, blh[kh], bll[kh]);
            loadWsplit(Wr, kh * 32 + g * 8, col, brh[kh], brl[kh]);
        }
        #pragma unroll
        for (int mt = 0; mt < 2; mt++) {
            f32x4 acc = {0.f, 0.f, 0.f, 0.f};
            #pragma unroll
            for (int kh = 0; kh < 2; kh++) {
                acc = __builtin_amdgcn_mfma_f32_16x16x32_bf16(axh[mt][kh], blh[kh], acc, 0, 0, 0);
                acc = __builtin_amdgcn_mfma_f32_16x16x32_bf16(axl[mt][kh], blh[kh], acc, 0, 0, 0);
                acc = __builtin_amdgcn_mfma_f32_16x16x32_bf16(axh[mt][kh], bll[kh], acc, 0, 0, 0);
                acc = __builtin_amdgcn_mfma_f32_16x16x32_bf16(ayh[mt][kh], brh[kh], acc, 0, 0, 0);
                acc = __builtin_amdgcn_mfma_f32_16x16x32_bf16(ayl[mt][kh], brh[kh], acc, 0, 0, 0);
                acc = __builtin_amdgcn_mfma_f32_16x16x32_bf16(ayh[mt][kh], brl[kh], acc, 0, 0, 0);
            }
            #pragma unroll
            for (int r = 0; r < 4; r++) {
                int row = r0 + mt * 16 + g * 4 + r;
                if (row < n)
                    out[(size_t)row * 64 + col] = f2bf(fmaxf(bl[col] + acc[r], 0.f));
            }
        }
    }
}

// sx = relu(b + agg@Wrel + state@Wroot)   (fp32 out; only read by dense sage)
__global__ __launch_bounds__(256)
void k_gc_mf(const float* __restrict__ agg, const float* __restrict__ st,
             const float* __restrict__ Wrel, const float* __restrict__ Wroot,
             const float* __restrict__ b, float* __restrict__ out, int n) {
    int wv = (int)(((long long)blockIdx.x * blockDim.x + threadIdx.x) >> 6);
    int lane = threadIdx.x & 63;
    int r0 = wv * 32;
    if (r0 >= n) return;
    int lm = lane & 15, g = lane >> 4;
    bf16x8 axh[2][2], axl[2][2], arh[2], arl[2];
    #pragma unroll
    for (int mt = 0; mt < 2; mt++) {
        int row = r0 + mt * 16 + lm; if (row >= n) row = n - 1;
        #pragma unroll
        for (int kh = 0; kh < 2; kh++)
            split8s(agg + (size_t)row * 64 + kh * 32 + g * 8, 1.f, axh[mt][kh], axl[mt][kh]);
        // root input: k = g*8+j, value st[row*6+k] for k<6 else 0
        #pragma unroll
        for (int j = 0; j < 8; j++) {
            int k = g * 8 + j;
            float v = (k < 6) ? st[(size_t)row * 6 + k] : 0.f;
            unsigned short hb = f2bf(v);
            arh[mt][j] = (short)hb;
            arl[mt][j] = (short)f2bf(v - bf2f(hb));
        }
    }
    #pragma unroll
    for (int nt = 0; nt < 4; nt++) {
        int col = nt * 16 + lm;
        bf16x8 bh[2], blo[2], brh, brl;
        #pragma unroll
        for (int kh = 0; kh < 2; kh++) loadWsplit(Wrel, kh * 32 + g * 8, col, bh[kh], blo[kh]);
        #pragma unroll
        for (int j = 0; j < 8; j++) {
            int k = g * 8 + j;
            float v = (k < 6) ? Wroot[(size_t)k * 64 + col] : 0.f;
            unsigned short hb = f2bf(v);
            brh[j] = (short)hb;
            brl[j] = (short)f2bf(v - bf2f(hb));
        }
        #pragma unroll
        for (int mt = 0; mt < 2; mt++) {
            f32x4 acc = {0.f, 0.f, 0.f, 0.f};
            #pragma unroll
            for (int kh = 0; kh < 2; kh++) {
                acc = __builtin_amdgcn_mfma_f32_16x16x32_bf16(axh[mt][kh], bh[kh],  acc, 0, 0, 0);
                acc = __builtin_amdgcn_mfma_f32_16x16x32_bf16(axl[mt][kh], bh[kh],  acc, 0, 0, 0);
                acc = __builtin_amdgcn_mfma_f32_16x16x32_bf16(axh[mt][kh], blo[kh], acc, 0, 0, 0);
            }
            acc = __builtin_amdgcn_mfma_f32_16x16x32_bf16(arh[mt], brh, acc, 0, 0, 0);
            acc = __builtin_amdgcn_mfma_f32_16x16x32_bf16(arl[mt], brh, acc, 0, 0, 0);
            acc = __builtin_amdgcn_mfma_f32_16x16x32_bf16(arh[mt], brl, acc, 0, 0, 0);
            #pragma unroll
            for (int r = 0; r < 4; r++) {
                int row = r0 + mt * 16 + g * 4 + r;
                if (row < n)
                    out[(size_t)row * 64 + col] = fmaxf(b[col] + acc[r], 0.f);
            }
        }
    }
}

// gx_bf = bf16(relu(b + x@W0 + h1@W1 + h2@W2))  (K=5 inputs; VALU is fine)
__global__ __launch_bounds__(256, 4)
void k_tag1_w(const float* __restrict__ x, const float* __restrict__ h1,
              const float* __restrict__ h2, const float* __restrict__ W,
              const float* __restrict__ b, unsigned short* __restrict__ out, int n) {
    int wv = (int)(((long long)blockIdx.x * blockDim.x + threadIdx.x) >> 6);
    int lane = threadIdx.x & 63;
    int i0 = wv * 4;
    if (i0 >= n) return;
    float v[4], acc[4];
    #pragma unroll
    for (int r = 0; r < 4; r++) {
        int i = (i0 + r < n) ? i0 + r : n - 1;
        float t = 0.f;
        if (lane < 5)                     t = x [(size_t)i * 5 + lane];
        else if (lane >= 8 && lane < 13)  t = h1[(size_t)i * 5 + lane - 8];
        else if (lane >= 16 && lane < 21) t = h2[(size_t)i * 5 + lane - 16];
        v[r] = t;
        acc[r] = b[lane];
    }
    #pragma unroll
    for (int m = 0; m < 3; m++) {
        #pragma unroll
        for (int k = 0; k < 5; k++) {
            float wk = W[(m * 5 + k) * 64 + lane];
            #pragma unroll
            for (int r = 0; r < 4; r++) acc[r] += bcast(v[r], m * 8 + k) * wk;
        }
    }
    #pragma unroll
    for (int r = 0; r < 4; r++)
        if (i0 + r < n) out[(size_t)(i0 + r) * 64 + lane] = f2bf(fmaxf(acc[r], 0.f));
}

__global__ void k_final(const float* __restrict__ x, const float* __restrict__ W,
                        const float* __restrict__ b, float* __restrict__ out, int n) {
    int t = blockIdx.x * blockDim.x + threadIdx.x;
    if (t >= n * 8) return;
    int i = t >> 3, o = t & 7;
    float acc = b[o];
    #pragma unroll 8
    for (int k = 0; k < 64; k++) acc += fmaxf(x[i * 64 + k], 0.f) * W[k * 8 + o];
    out[t] = acc;
}

static inline unsigned gblk(long long n) { return (unsigned)((n + BLK - 1) / BLK); }
static inline unsigned gwv4(long long n) { return gblk(((n + 3) / 4) * 64); }
static inline unsigned gw32(long long n) { return gblk(((n + 31) / 32) * 64); }

extern "C" void kernel_launch(void* const* d_in, const int* in_sizes, int n_in,
                              void* d_out, int out_size, void* d_ws, size_t ws_size,
                              hipStream_t stream) {
    const float* game_x  = (const float*)d_in[0];
    const float* state_x = (const float*)d_in[1];
    const int*   ei_vv   = (const int*)d_in[2];
    const int*   ei_h    = (const int*)d_in[3];
    const float* ea_h    = (const float*)d_in[4];
    const int*   ei_in   = (const int*)d_in[5];
    const int*   ei_ss   = (const int*)d_in[6];
    const float* tag1_W  = (const float*)d_in[7];
    const float* tag1_b  = (const float*)d_in[8];
    const float* tag2_W  = (const float*)d_in[9];
    const float* tag2_b  = (const float*)d_in[10];
    const float* gc_Wrel = (const float*)d_in[11];
    const float* gc_b    = (const float*)d_in[12];
    const float* gc_Wroot= (const float*)d_in[13];
    const float* sage_Wl = (const float*)d_in[14];
    const float* sage_bl = (const float*)d_in[15];
    const float* sage_Wr = (const float*)d_in[16];
    const float* lin_W   = (const float*)d_in[17];
    const float* lin_b   = (const float*)d_in[18];

    const int NV  = in_sizes[0] / 5;
    const int NS  = in_sizes[1] / 6;
    const int EVV = in_sizes[2] / 2;
    const int EH  = in_sizes[3] / 2;
    const int EIN = in_sizes[5] / 2;
    const int ESS = in_sizes[6] / 2;

    const int *vv_s = ei_vv,  *vv_d = ei_vv + EVV;
    const int *h_s  = ei_h,   *h_d  = ei_h  + EH;
    const int *in_s = ei_in,  *in_d = ei_in + EIN;
    const int *ss_s = ei_ss,  *ss_d = ei_ss + ESS;

    // bin geometry
    const int ncv = (EVV + ACH - 1) / ACH;
    const int nch = (EH  + ACH - 1) / ACH;
    const int nci = (EIN + ACH - 1) / ACH;
    const int ncs = (ESS + ACH - 1) / ACH;
    const int nbv_ = (NV + 255) >> 8;   // bin width 256 over NV dsts
    const int nbs_ = (NS + 127) >> 7;   // bin width 128 over NS dsts
    const int Lv = nbv_ * ncv, Lh = nbs_ * nch, Li = nbs_ * nci, Ls = nbs_ * ncs;
    const int nB0 = (Lv + 255) / 256, nB1 = (Lh + 255) / 256,
              nB2 = (Li + 255) / 256, nB3 = (Ls + 255) / 256;

    // ---------------- workspace layout (4-byte words) ----------------
    float* wsf = (float*)d_ws;
    size_t o = 0;
    unsigned short* gx_bf = (unsigned short*)(wsf + o);   // NV x 64 bf16
    float* sx3 = wsf + o; o += (size_t)NV * 32;           // alias (NS*64 fp32 == NV*32 words)
    float* B1 = wsf + o; o += (size_t)NS * 64;            // binned vv|in|ss (phase0) | agg | ssum | hA_bf
    float* B2 = wsf + o; o += (size_t)NS * 64;            // binned h (phase0) | sx | hB_bf
    float* B4 = wsf + o; o += (size_t)NS * 32;            // h1v+h2v (NV*10) | sx2_bf (NS*32)
    int*  vvsrc = (int*)(wsf + o); o += (size_t)EVV;
    int*  sssrc = (int*)(wsf + o); o += (size_t)ESS;
    int*  insrc = (int*)(wsf + o); o += (size_t)EIN;
    int2* hsw   = (int2*)(wsf + o); o += (size_t)EH * 2;
    int* T_all = (int*)(wsf + o); o += (size_t)(Lv + Lh + Li + Ls);
    int* bsum  = (int*)(wsf + o); o += 2048;              // scan block sums
    int* rv = (int*)(wsf + o); o += (size_t)NV + 1;
    int* rh = (int*)(wsf + o); o += (size_t)NS + 1;
    int* ri = (int*)(wsf + o); o += (size_t)NS + 1;
    int* rs = (int*)(wsf + o); o += (size_t)NS + 1;
    float* dinv_v = wsf + o; o += (size_t)NV;
    float* dinv_s = wsf + o; o += (size_t)NS;

    int* Tv = T_all;
    int* Th = Tv + Lv;
    int* Ti = Th + Lh;
    int* Ts = Ti + Li;

    // phase-0 binned edge buffers alias B1/B2 (dead until stage B)
    unsigned* vvbin = (unsigned*)B1;
    unsigned* inbin = vvbin + EVV;
    unsigned* ssbin = inbin + EIN;
    int2* hbin = (int2*)B2;

    unsigned short* hA_bf  = (unsigned short*)B1;
    unsigned short* hB_bf  = (unsigned short*)B2;
    unsigned short* sx2_bf = (unsigned short*)B4;

    // ================= Phase 0: atomic-free batched CSR build =================
    int nbins   = nbv_ + 3 * nbs_;
    int nBtot   = nB0 + nB1 + nB2 + nB3;
    k_binA1<<<ncv + nch + nci + ncs, 256, 0, stream>>>(vv_d, h_d, in_d, ss_d, Tv, Th, Ti, Ts,
                                         ncv, nch, nci, ncs, nbv_, nbs_,
                                         EVV, EH, EIN, ESS);
    k_sb2<<<nBtot, 256, 0, stream>>>(T_all, bsum, Lv, Lh, Li, Ls, nB0, nB1, nB2, nB3);
    k_st2<<<4, 1024, 0, stream>>>(bsum, nB0, nB1, nB2, nB3);
    k_sa2<<<nBtot, 256, 0, stream>>>(T_all, bsum, Lv, Lh, Li, Ls, nB0, nB1, nB2, nB3);
    k_binA2a<<<ncv + nci + ncs, 512, 0, stream>>>(vv_s, vv_d, in_s, in_d, ss_s, ss_d,
                                                  Tv, Ti, Ts, vvbin, inbin, ssbin,
                                                  ncv, nci, ncs, nbv_, nbs_,
                                                  EVV, EIN, ESS);
    k_binA2h<<<nch, 512, 0, stream>>>(h_s, h_d, ea_h, Th, hbin, nch, nbs_, EH);
    k_binB<<<nbins, 256, 0, stream>>>(vvbin, hbin, inbin, ssbin,
                                      Tv, Th, Ti, Ts,
                                      rv, rh, ri, rs, dinv_v, dinv_s,
                                      vvsrc, hsw, insrc, sssrc,
                                      ncv, nch, nci, ncs, nbv_, nbs_,
                                      NV, NS, EVV, EH, EIN, ESS);

    // ================= Stage A: TAGConv1 on v-v =================
    float* h1v = B4;
    float* h2v = B4 + (size_t)NV * 5;
    k_gather5<<<gblk(NV), BLK, 0, stream>>>(game_x, rv, vvsrc, dinv_v, h1v, NV);
    k_gather5<<<gblk(NV), BLK, 0, stream>>>(h1v,    rv, vvsrc, dinv_v, h2v, NV);
    k_tag1_w<<<gwv4(NV), BLK, 0, stream>>>(game_x, h1v, h2v, tag1_W, tag1_b, gx_bf, NV);

    // ================= Stage B: GraphConv (weighted) =================
    k_gather64<1, false><<<gblk((long long)NS * 64), BLK, 0, stream>>>(gx_bf, rh, nullptr, hsw, nullptr, B1, NS);
    k_gc_mf<<<gw32(NS), BLK, 0, stream>>>(B1, state_x, gc_Wrel, gc_Wroot, gc_b, B2, NS);

    // ================= Stage C: SAGE mean =================
    k_gather64<0, false><<<gblk((long long)NS * 64), BLK, 0, stream>>>(gx_bf, ri, insrc, nullptr, nullptr, B1, NS);
    k_sage_mf<<<gw32(NS), BLK, 0, stream>>>(B1, ri, B2, sage_Wl, sage_Wr, sage_bl, sx2_bf, NS);

    // ================= Stage D: TAGConv2 on s-s (K=3) =================
    // gx_bf dead -> sx3 alias; B1 (ssum) dead -> hA_bf; B2 (sx) dead -> hB_bf
    k_mm_mf<true><<<gw32(NS), BLK, 0, stream>>>(sx2_bf, tag2_W, tag2_b, sx3, NS);
    k_gather64<2, true><<<gblk((long long)NS * 64), BLK, 0, stream>>>(sx2_bf, rs, sssrc, nullptr, dinv_s, hA_bf, NS);
    k_mm_mf<false><<<gw32(NS), BLK, 0, stream>>>(hA_bf, tag2_W + 4096, nullptr, sx3, NS);
    k_gather64<2, true><<<gblk((long long)NS * 64), BLK, 0, stream>>>(hA_bf, rs, sssrc, nullptr, dinv_s, hB_bf, NS);
    k_mm_mf<false><<<gw32(NS), BLK, 0, stream>>>(hB_bf, tag2_W + 8192, nullptr, sx3, NS);
    k_gather64<2, true><<<gblk((long long)NS * 64), BLK, 0, stream>>>(hB_bf, rs, sssrc, nullptr, dinv_s, hA_bf, NS);
    k_mm_mf<false><<<gw32(NS), BLK, 0, stream>>>(hA_bf, tag2_W + 12288, nullptr, sx3, NS);

    // ================= Stage E: final linear (relu fused) =================
    k_final<<<gblk((long long)NS * 8), BLK, 0, stream>>>(sx3, lin_W, lin_b, (float*)d_out, NS);
}

// Round 5
// 395.584 us; speedup vs baseline: 1.6565x; 1.0962x over previous
//
#include <hip/hip_runtime.h>

#define BLK 256
#define ACH 4096   // edges per block in bin passes

// broadcast lane l of v across the wave (l wave-uniform; dynamic is legal)
__device__ __forceinline__ float bcast(float v, int l) {
    return __int_as_float(__builtin_amdgcn_readlane(__float_as_int(v), l));
}
// fp32 <-> bf16 (round-to-nearest-even)
__device__ __forceinline__ unsigned short f2bf(float f) {
    unsigned u = __float_as_uint(f);
    return (unsigned short)((u + 0x7FFFu + ((u >> 16) & 1u)) >> 16);
}
__device__ __forceinline__ float bf2f(unsigned short b) {
    return __uint_as_float(((unsigned)b) << 16);
}

// ---------------- MFMA fragment types ------
typedef __attribute__((ext_vector_type(8))) short bf16x8;
typedef __attribute__((ext_vector_type(4))) float f32x4;

// split 8 fp32 (scaled) into hi/lo bf16 fragments: v ~= hi + lo
__device__ __forceinline__ void split8s(const float* p, float s, bf16x8& h, bf16x8& l) {
    #pragma unroll
    for (int j = 0; j < 8; j++) {
        float v = p[j] * s;
        unsigned short hb = f2bf(v);
        h[j] = (short)hb;
        l[j] = (short)f2bf(v - bf2f(hb));
    }
}
// gather W[kbase+j][col] (stride-64 fp32), split hi/lo
__device__ __forceinline__ void loadWsplit(const float* W, int kbase, int col,
                                           bf16x8& h, bf16x8& l) {
    #pragma unroll
    for (int j = 0; j < 8; j++) {
        float v = W[(size_t)(kbase + j) * 64 + col];
        unsigned short hb = f2bf(v);
        h[j] = (short)hb;
        l[j] = (short)f2bf(v - bf2f(hb));
    }
}

// ================= atomic-free CSR build (two-level binned counting sort) ====

__global__ void k_binA1(const int* __restrict__ vd, const int* __restrict__ hd,
                        const int* __restrict__ id_, const int* __restrict__ sd,
                        int* __restrict__ Tv, int* __restrict__ Th,
                        int* __restrict__ Ti, int* __restrict__ Ts,
                        int ncv, int nch, int nci, int ncs,
                        int nbv_, int nbs_, int Ev, int Eh, int Ei, int Es) {
    __shared__ int cnt[512];
    int blk = blockIdx.x, t = threadIdx.x;
    const int* dd; int* T; int c, nc, nb, E, sf;
    if (blk < ncv)                 { dd = vd;  T = Tv; c = blk;               nc = ncv; nb = nbv_; E = Ev; sf = 8; }
    else if (blk < ncv + nch)      { dd = hd;  T = Th; c = blk - ncv;         nc = nch; nb = nbs_; E = Eh; sf = 7; }
    else if (blk < ncv + nch + nci){ dd = id_; T = Ti; c = blk - ncv - nch;   nc = nci; nb = nbs_; E = Ei; sf = 7; }
    else                           { dd = sd;  T = Ts; c = blk - ncv - nch - nci; nc = ncs; nb = nbs_; E = Es; sf = 7; }
    cnt[t] = 0; cnt[t + 256] = 0;
    __syncthreads();
    int p0 = c * ACH, p1 = min(E, p0 + ACH);
    for (int p = p0 + t; p < p1; p += 256) atomicAdd(&cnt[dd[p] >> sf], 1);
    __syncthreads();
    for (int b = t; b < nb; b += 256) T[(size_t)b * nc + c] = cnt[b];
}

// 3-level exclusive scan over the 4 concatenated T arrays (in place)
__global__ void k_sb2(int* __restrict__ T, int* __restrict__ bsum,
                      int L0, int L1, int L2, int L3,
                      int nB0, int nB1, int nB2, int nB3) {
    __shared__ int sh[256];
    int blk = blockIdx.x;
    int lb, off, L;
    if (blk < nB0)                  { lb = blk;                 off = 0;            L = L0; }
    else if (blk < nB0 + nB1)       { lb = blk - nB0;           off = L0;           L = L1; }
    else if (blk < nB0 + nB1 + nB2) { lb = blk - nB0 - nB1;     off = L0 + L1;      L = L2; }
    else                            { lb = blk - nB0 - nB1 - nB2; off = L0 + L1 + L2; L = L3; }
    int i = lb * 256 + threadIdx.x;
    int v = (i < L) ? T[off + i] : 0;
    sh[threadIdx.x] = v; __syncthreads();
    for (int o2 = 1; o2 < 256; o2 <<= 1) {
        int tmp = (threadIdx.x >= o2) ? sh[threadIdx.x - o2] : 0;
        __syncthreads();
        sh[threadIdx.x] += tmp; __syncthreads();
    }
    if (i < L) T[off + i] = sh[threadIdx.x] - v;
    if (threadIdx.x == 255) bsum[blk] = sh[255];
}

__global__ void k_st2(int* __restrict__ bsum, int nB0, int nB1, int nB2, int nB3) {
    __shared__ int sh[1024];
    int g = blockIdx.x;
    int off = (g == 0) ? 0 : (g == 1) ? nB0 : (g == 2) ? nB0 + nB1 : nB0 + nB1 + nB2;
    int nb  = (g == 0) ? nB0 : (g == 1) ? nB1 : (g == 2) ? nB2 : nB3;
    int tid = threadIdx.x;
    int v = (tid < nb) ? bsum[off + tid] : 0;
    sh[tid] = v; __syncthreads();
    for (int o2 = 1; o2 < 1024; o2 <<= 1) {
        int t = (tid >= o2) ? sh[tid - o2] : 0;
        __syncthreads();
        sh[tid] += t; __syncthreads();
    }
    if (tid < nb) bsum[off + tid] = sh[tid] - v;
}

__global__ void k_sa2(int* __restrict__ T, const int* __restrict__ bsum,
                      int L0, int L1, int L2, int L3,
                      int nB0, int nB1, int nB2, int nB3) {
    int blk = blockIdx.x;
    int lb, off, L;
    if (blk < nB0)                  { lb = blk;                 off = 0;            L = L0; }
    else if (blk < nB0 + nB1)       { lb = blk - nB0;           off = L0;           L = L1; }
    else if (blk < nB0 + nB1 + nB2) { lb = blk - nB0 - nB1;     off = L0 + L1;      L = L2; }
    else                            { lb = blk - nB0 - nB1 - nB2; off = L0 + L1 + L2; L = L3; }
    int i = lb * 256 + threadIdx.x;
    if (i < L) T[off + i] += bsum[blk];
}

// A2 (no-weight graphs vv/in/ss): register-stage 8 edges/thread, LDS counting
// sort by bin, stream out -> piecewise-contiguous global writes.
__global__ __launch_bounds__(512)
void k_binA2a(const int* __restrict__ vs, const int* __restrict__ vd,
              const int* __restrict__ is_, const int* __restrict__ id_,
              const int* __restrict__ ss_, const int* __restrict__ sd,
              const int* __restrict__ Tv, const int* __restrict__ Ti,
              const int* __restrict__ Ts,
              unsigned* __restrict__ vvbin, unsigned* __restrict__ inbin,
              unsigned* __restrict__ ssbin,
              int ncv, int nci, int ncs, int nbv_, int nbs_,
              int Ev, int Ei, int Es) {
    __shared__ int gbase[512], lscan[512], lcur[512];
    __shared__ unsigned sval[ACH];
    __shared__ int sdst[ACH];
    int blk = blockIdx.x, t = threadIdx.x;
    const int *srcp, *dstp, *T; unsigned* bin; int c, nc, nb, E, sf;
    if (blk < ncv)            { srcp = vs;  dstp = vd;  T = Tv; bin = vvbin; c = blk;             nc = ncv; nb = nbv_; E = Ev; sf = 8; }
    else if (blk < ncv + nci) { srcp = is_; dstp = id_; T = Ti; bin = inbin; c = blk - ncv;       nc = nci; nb = nbs_; E = Ei; sf = 7; }
    else                      { srcp = ss_; dstp = sd;  T = Ts; bin = ssbin; c = blk - ncv - nci; nc = ncs; nb = nbs_; E = Es; sf = 7; }
    int msk = (1 << sf) - 1;
    int p0 = c * ACH, p1 = min(E, p0 + ACH);
    if (t < nb) gbase[t] = T[(size_t)t * nc + c];
    lcur[t] = 0;
    int myS[8], myD[8];
    #pragma unroll
    for (int i = 0; i < 8; i++) {
        int p = p0 + t + i * 512;
        if (p < p1) { myS[i] = srcp[p]; myD[i] = dstp[p]; }
        else myD[i] = -1;
    }
    __syncthreads();
    #pragma unroll
    for (int i = 0; i < 8; i++)
        if (myD[i] >= 0) atomicAdd(&lcur[myD[i] >> sf], 1);
    __syncthreads();
    int v = lcur[t];
    lscan[t] = v;
    __syncthreads();
    for (int off = 1; off < 512; off <<= 1) {
        int tmp = (t >= off) ? lscan[t - off] : 0;
        __syncthreads();
        lscan[t] += tmp;
        __syncthreads();
    }
    int excl = lscan[t] - v;
    __syncthreads();
    lscan[t] = excl;
    lcur[t] = 0;
    __syncthreads();
    #pragma unroll
    for (int i = 0; i < 8; i++) {
        if (myD[i] < 0) continue;
        int b = myD[i] >> sf;
        int r = atomicAdd(&lcur[b], 1);
        int pos = lscan[b] + r;
        sval[pos] = ((unsigned)myS[i] << sf) | (unsigned)(myD[i] & msk);
        sdst[pos] = gbase[b] + r;
    }
    __syncthreads();
    int cntE = p1 - p0;
    for (int q = t; q < cntE; q += 512) bin[sdst[q]] = sval[q];
}

// A2 for the weighted h graph (int2 payload)
__global__ __launch_bounds__(512)
void k_binA2h(const int* __restrict__ hs, const int* __restrict__ hd,
              const float* __restrict__ hw, const int* __restrict__ Th,
              int2* __restrict__ hbin, int nch, int nbs_, int Eh) {
    __shared__ int gbase[512], lscan[512], lcur[512];
    __shared__ unsigned sval[ACH];
    __shared__ int sdst[ACH];
    __shared__ float swt[ACH];
    int c = blockIdx.x, t = threadIdx.x;
    const int sf = 7, msk = 127;
    int p0 = c * ACH, p1 = min(Eh, p0 + ACH);
    if (t < nbs_) gbase[t] = Th[(size_t)t * nch + c];
    lcur[t] = 0;
    int myS[8], myD[8]; float myW[8];
    #pragma unroll
    for (int i = 0; i < 8; i++) {
        int p = p0 + t + i * 512;
        if (p < p1) { myS[i] = hs[p]; myD[i] = hd[p]; myW[i] = hw[p]; }
        else myD[i] = -1;
    }
    __syncthreads();
    #pragma unroll
    for (int i = 0; i < 8; i++)
        if (myD[i] >= 0) atomicAdd(&lcur[myD[i] >> sf], 1);
    __syncthreads();
    int v = lcur[t];
    lscan[t] = v;
    __syncthreads();
    for (int off = 1; off < 512; off <<= 1) {
        int tmp = (t >= off) ? lscan[t - off] : 0;
        __syncthreads();
        lscan[t] += tmp;
        __syncthreads();
    }
    int excl = lscan[t] - v;
    __syncthreads();
    lscan[t] = excl;
    lcur[t] = 0;
    __syncthreads();
    #pragma unroll
    for (int i = 0; i < 8; i++) {
        if (myD[i] < 0) continue;
        int b = myD[i] >> sf;
        int r = atomicAdd(&lcur[b], 1);
        int pos = lscan[b] + r;
        sval[pos] = ((unsigned)myS[i] << sf) | (unsigned)(myD[i] & msk);
        sdst[pos] = gbase[b] + r;
        swt[pos] = myW[i];
    }
    __syncthreads();
    int cntE = p1 - p0;
    for (int q = t; q < cntE; q += 512)
        hbin[sdst[q]] = make_int2((int)sval[q], __float_as_int(swt[q]));
}

__global__ void k_binB(const unsigned* __restrict__ vvbin, const int2* __restrict__ hbin,
                       const unsigned* __restrict__ inbin, const unsigned* __restrict__ ssbin,
                       const int* __restrict__ Tv, const int* __restrict__ Th,
                       const int* __restrict__ Ti, const int* __restrict__ Ts,
                       int* __restrict__ rv, int* __restrict__ rh,
                       int* __restrict__ ri, int* __restrict__ rs,
                       float* __restrict__ dinv_v, float* __restrict__ dinv_s,
                       int* __restrict__ vvsrc, int2* __restrict__ hsw,
                       int* __restrict__ insrc, int* __restrict__ sssrc,
                       int ncv, int nch, int nci, int ncs,
                       int nbv_, int nbs_, int nv, int ns,
                       int Ev, int Eh, int Ei, int Es) {
    __shared__ int cnt[256]; __shared__ int pre[256]; __shared__ int cur[256];
    int blk = blockIdx.x, t = threadIdx.x;
    int g, b, nb, nc, sf, n, E; const int* T; int* rp;
    if (blk < nbv_)                 { g = 0; b = blk;                 nb = nbv_; nc = ncv; sf = 8; n = nv; E = Ev; T = Tv; rp = rv; }
    else if (blk < nbv_ + nbs_)     { g = 1; b = blk - nbv_;          nb = nbs_; nc = nch; sf = 7; n = ns; E = Eh; T = Th; rp = rh; }
    else if (blk < nbv_ + 2 * nbs_) { g = 2; b = blk - nbv_ - nbs_;   nb = nbs_; nc = nci; sf = 7; n = ns; E = Ei; T = Ti; rp = ri; }
    else                            { g = 3; b = blk - nbv_ - 2 * nbs_; nb = nbs_; nc = ncs; sf = 7; n = ns; E = Es; T = Ts; rp = rs; }
    int W = 1 << sf, msk = W - 1;
    int e0 = T[(size_t)b * nc];
    int e1 = (b + 1 < nb) ? T[(size_t)(b + 1) * nc] : E;
    cnt[t] = 0; __syncthreads();
    for (int p = e0 + t; p < e1; p += 256) {
        unsigned pk = (g == 1) ? (unsigned)hbin[p].x
                    : (g == 0) ? vvbin[p] : (g == 2) ? inbin[p] : ssbin[p];
        atomicAdd(&cnt[pk & msk], 1);
    }
    __syncthreads();
    int v = cnt[t];
    pre[t] = v; __syncthreads();
    for (int o2 = 1; o2 < 256; o2 <<= 1) {
        int tmp = (t >= o2) ? pre[t - o2] : 0;
        __syncthreads();
        pre[t] += tmp; __syncthreads();
    }
    int excl = pre[t] - v;
    int d = b * W + t;
    if (t < W && d < n) {
        rp[d] = e0 + excl;
        if (g == 0)      dinv_v[d] = v > 0 ? rsqrtf((float)v) : 0.f;
        else if (g == 3) dinv_s[d] = v > 0 ? rsqrtf((float)v) : 0.f;
    }
    cur[t] = e0 + excl;
    __syncthreads();
    for (int p = e0 + t; p < e1; p += 256) {
        if (g == 1) {
            int2 r = hbin[p];
            unsigned pk = (unsigned)r.x;
            int pos = atomicAdd(&cur[pk & msk], 1);
            hsw[pos] = make_int2((int)(pk >> sf), r.y);
        } else {
            unsigned pk = (g == 0) ? vvbin[p] : (g == 2) ? inbin[p] : ssbin[p];
            int pos = atomicAdd(&cur[pk & msk], 1);
            int sv = (int)(pk >> sf);
            if (g == 0)      vvsrc[pos] = sv;
            else if (g == 2) insrc[pos] = sv;
            else             sssrc[pos] = sv;
        }
    }
    if (b == 0 && t == 0) rp[n] = E;
}

// ================= gathers =================

// pack (x[5], dinv) into one aligned 32B fp32 packet per node: one cacheline
// per edge read, no separate dependent dinv load. Numerics identical (fp32).
__global__ void k_pack5(const float* __restrict__ x, const float* __restrict__ dinv,
                        float* __restrict__ P, int n) {
    int i = blockIdx.x * blockDim.x + threadIdx.x;
    if (i >= n) return;
    const float* xp = x + (size_t)i * 5;
    float4 a = make_float4(xp[0], xp[1], xp[2], xp[3]);
    float4 b = make_float4(xp[4], dinv[i], 0.f, 0.f);
    ((float4*)P)[(size_t)i * 2]     = a;
    ((float4*)P)[(size_t)i * 2 + 1] = b;
}

// gather over 32B packets; output is also a packet (h[5], dinv) for the next hop
__global__ void k_gather5p(const float* __restrict__ Pin, const int* __restrict__ rowptr,
                           const int* __restrict__ csr_src, float* __restrict__ Pout, int n) {
    int d = blockIdx.x * blockDim.x + threadIdx.x;
    if (d >= n) return;
    int b = rowptr[d], e = rowptr[d + 1];
    float dd = Pin[(size_t)d * 8 + 5];
    float a0 = 0, a1 = 0, a2 = 0, a3 = 0, a4 = 0;
    int p = b;
    for (; p + 4 <= e; p += 4) {
        int s0 = csr_src[p], s1 = csr_src[p+1], s2 = csr_src[p+2], s3 = csr_src[p+3];
        float4 x0a = ((const float4*)Pin)[(size_t)s0 * 2], x0b = ((const float4*)Pin)[(size_t)s0 * 2 + 1];
        float4 x1a = ((const float4*)Pin)[(size_t)s1 * 2], x1b = ((const float4*)Pin)[(size_t)s1 * 2 + 1];
        float4 x2a = ((const float4*)Pin)[(size_t)s2 * 2], x2b = ((const float4*)Pin)[(size_t)s2 * 2 + 1];
        float4 x3a = ((const float4*)Pin)[(size_t)s3 * 2], x3b = ((const float4*)Pin)[(size_t)s3 * 2 + 1];
        float w0 = dd * x0b.y, w1 = dd * x1b.y, w2 = dd * x2b.y, w3 = dd * x3b.y;
        a0 += x0a.x*w0 + x1a.x*w1 + x2a.x*w2 + x3a.x*w3;
        a1 += x0a.y*w0 + x1a.y*w1 + x2a.y*w2 + x3a.y*w3;
        a2 += x0a.z*w0 + x1a.z*w1 + x2a.z*w2 + x3a.z*w3;
        a3 += x0a.w*w0 + x1a.w*w1 + x2a.w*w2 + x3a.w*w3;
        a4 += x0b.x*w0 + x1b.x*w1 + x2b.x*w2 + x3b.x*w3;
    }
    for (; p < e; p++) {
        int s = csr_src[p];
        float4 xa = ((const float4*)Pin)[(size_t)s * 2], xb = ((const float4*)Pin)[(size_t)s * 2 + 1];
        float w = dd * xb.y;
        a0 += xa.x*w; a1 += xa.y*w; a2 += xa.z*w; a3 += xa.w*w; a4 += xb.x*w;
    }
    ((float4*)Pout)[(size_t)d * 2]     = make_float4(a0, a1, a2, a3);
    ((float4*)Pout)[(size_t)d * 2 + 1] = make_float4(a4, dd, 0.f, 0.f);
}

// 64-ch gather over bf16 rows: wave per dst row; 4 groups x 16 lanes x ushort4(8B);
// 4-edge-deep MLP; fp32 accumulate.
// MODE: 0 = plain sum, 1 = per-edge weight (int2 packed), 2 = symmetric gcn norm
// OUTBF: write bf16 row (for next gather hop) vs fp32 row
template<int MODE, bool OUTBF>
__global__ void k_gather64(const unsigned short* __restrict__ xbf, const int* __restrict__ rowptr,
                           const int* __restrict__ csr_src, const int2* __restrict__ csr_sw,
                           const float* __restrict__ dinv, void* __restrict__ outp, int n) {
    int wid = (int)(((long long)blockIdx.x * blockDim.x + threadIdx.x) >> 6);
    if (wid >= n) return;
    int lane = threadIdx.x & 63;
    int g = lane >> 4, q = lane & 15;
    int b = rowptr[wid], e = rowptr[wid + 1];
    float dd = (MODE == 2) ? dinv[wid] : 0.f;
    float4 acc = make_float4(0.f, 0.f, 0.f, 0.f);
    int p = b + g;
    for (; p + 12 < e; p += 16) {
        int s0, s1, s2, s3;
        float w0 = 1.f, w1 = 1.f, w2 = 1.f, w3 = 1.f;
        if (MODE == 1) {
            int2 e0 = csr_sw[p], e1 = csr_sw[p+4], e2 = csr_sw[p+8], e3 = csr_sw[p+12];
            s0 = e0.x; w0 = __int_as_float(e0.y);
            s1 = e1.x; w1 = __int_as_float(e1.y);
            s2 = e2.x; w2 = __int_as_float(e2.y);
            s3 = e3.x; w3 = __int_as_float(e3.y);
        } else {
            s0 = csr_src[p]; s1 = csr_src[p+4]; s2 = csr_src[p+8]; s3 = csr_src[p+12];
            if (MODE == 2) {
                w0 = dd * dinv[s0]; w1 = dd * dinv[s1];
                w2 = dd * dinv[s2]; w3 = dd * dinv[s3];
            }
        }
        ushort4 u0 = ((const ushort4*)(xbf + (size_t)s0 * 64))[q];
        ushort4 u1 = ((const ushort4*)(xbf + (size_t)s1 * 64))[q];
        ushort4 u2 = ((const ushort4*)(xbf + (size_t)s2 * 64))[q];
        ushort4 u3 = ((const ushort4*)(xbf + (size_t)s3 * 64))[q];
        acc.x += bf2f(u0.x)*w0 + bf2f(u1.x)*w1 + bf2f(u2.x)*w2 + bf2f(u3.x)*w3;
        acc.y += bf2f(u0.y)*w0 + bf2f(u1.y)*w1 + bf2f(u2.y)*w2 + bf2f(u3.y)*w3;
        acc.z += bf2f(u0.z)*w0 + bf2f(u1.z)*w1 + bf2f(u2.z)*w2 + bf2f(u3.z)*w3;
        acc.w += bf2f(u0.w)*w0 + bf2f(u1.w)*w1 + bf2f(u2.w)*w2 + bf2f(u3.w)*w3;
    }
    for (; p < e; p += 4) {
        int s; float w = 1.f;
        if (MODE == 1) { int2 e0 = csr_sw[p]; s = e0.x; w = __int_as_float(e0.y); }
        else { s = csr_src[p]; if (MODE == 2) w = dd * dinv[s]; }
        ushort4 u = ((const ushort4*)(xbf + (size_t)s * 64))[q];
        acc.x += bf2f(u.x)*w; acc.y += bf2f(u.y)*w;
        acc.z += bf2f(u.z)*w; acc.w += bf2f(u.w)*w;
    }
    #pragma unroll
    for (int off = 16; off < 64; off <<= 1) {
        acc.x += __shfl_xor(acc.x, off, 64);
        acc.y += __shfl_xor(acc.y, off, 64);
        acc.z += __shfl_xor(acc.z, off, 64);
        acc.w += __shfl_xor(acc.w, off, 64);
    }
    if (g == 0) {
        if (OUTBF) {
            ushort4 ov;
            ov.x = f2bf(acc.x); ov.y = f2bf(acc.y); ov.z = f2bf(acc.z); ov.w = f2bf(acc.w);
            ((ushort4*)outp)[(size_t)wid * 16 + q] = ov;
        } else {
            ((float4*)outp)[(size_t)wid * 16 + q] = acc;
        }
    }
}

// ============ dense combines (MFMA wave GEMMs, 32 rows x 64 cols/wave) =======
// k-map: A and B both loaded with k = kh*32 + g*8 + j (g = lane>>4, j = elem).
// C/D layout (HW-verified): col = lane&15, row = g*4 + reg.

// sx2_bf = bf16(relu(bl + (ssum/max(cnt,1))@Wl + sx@Wr))
__global__ __launch_bounds__(256)
void k_sage_mf(const float* __restrict__ ssum, const int* __restrict__ rp,
               const float* __restrict__ sx, const float* __restrict__ Wl,
               const float* __restrict__ Wr, const float* __restrict__ bl,
               unsigned short* __restrict__ out, int n) {
    int wv = (int)(((long long)blockIdx.x * blockDim.x + threadIdx.x) >> 6);
    int lane = threadIdx.x & 63;
    int r0 = wv * 32;
    if (r0 >= n) return;
    int lm = lane & 15, g = lane >> 4;
    bf16x8 axh[2][2], axl[2][2], ayh[2][2], ayl[2][2];
    #pragma unroll
    for (int mt = 0; mt < 2; mt++) {
        int row = r0 + mt * 16 + lm; if (row >= n) row = n - 1;
        float cnt = (float)(rp[row + 1] - rp[row]);
        float rs = 1.f / fmaxf(cnt, 1.f);
        #pragma unroll
        for (int kh = 0; kh < 2; kh++) {
            split8s(ssum + (size_t)row * 64 + kh * 32 + g * 8, rs,  axh[mt][kh], axl[mt][kh]);
            split8s(sx   + (size_t)row * 64 + kh * 32 + g * 8, 1.f, ayh[mt][kh], ayl[mt][kh]);
        }
    }
    #pragma unroll
    for (int nt = 0; nt < 4; nt++) {
        int col = nt * 16 + lm;
        bf16x8 blh[2], bll[2], brh[2], brl[2];
        #pragma unroll
        for (int kh = 0; kh < 2; kh++) {
            loadWsplit(Wl, kh * 32 + g * 8, col, blh[kh], bll[kh]);
            loadWsplit(Wr, kh * 32 + g * 8, col, brh[kh], brl[kh]);
        }
        #pragma unroll
        for (int mt = 0; mt < 2; mt++) {
            f32x4 acc = {0.f, 0.f, 0.f, 0.f};
            #pragma unroll
            for (int kh = 0; kh < 2; kh++) {
                acc = __builtin_amdgcn_mfma_f32_16x16x32_bf16(axh[mt][kh], blh[kh], acc, 0, 0, 0);
                acc = __builtin_amdgcn_mfma_f32_16x16x32_bf16(axl[mt][kh], blh[kh], acc, 0, 0, 0);
                acc = __builtin_amdgcn_mfma_f32_16x16x32_bf16(axh[mt][kh], bll[kh], acc, 0, 0, 0);
                acc = __builtin_amdgcn_mfma_f32_16x16x32_bf16(ayh[mt][kh], brh[kh], acc, 0, 0, 0);
                acc = __builtin_amdgcn_mfma_f32_16x16x32_bf16(ayl[mt][kh], brh[kh], acc, 0, 0, 0);
                acc = __builtin_amdgcn_mfma_f32_16x16x32_bf16(ayh[mt][kh], brl[kh], acc, 0, 0, 0);
            }
            #pragma unroll
            for (int r = 0; r < 4; r++) {
                int row = r0 + mt * 16 + g * 4 + r;
                if (row < n)
                    out[(size_t)row * 64 + col] = f2bf(fmaxf(bl[col] + acc[r], 0.f));
            }
        }
    }
}

// sx = relu(b + agg@Wrel + state@Wroot)   (fp32 out; only read by dense sage)
__global__ __launch_bounds__(256)
void k_gc_mf(const float* __restrict__ agg, const float* __restrict__ st,
             const float* __restrict__ Wrel, const float* __restrict__ Wroot,
             const float* __restrict__ b, float* __restrict__ out, int n) {
    int wv = (int)(((long long)blockIdx.x * blockDim.x + threadIdx.x) >> 6);
    int lane = threadIdx.x & 63;
    int r0 = wv * 32;
    if (r0 >= n) return;
    int lm = lane & 15, g = lane >> 4;
    bf16x8 axh[2][2], axl[2][2], arh[2], arl[2];
    #pragma unroll
    for (int mt = 0; mt < 2; mt++) {
        int row = r0 + mt * 16 + lm; if (row >= n) row = n - 1;
        #pragma unroll
        for (int kh = 0; kh < 2; kh++)
            split8s(agg + (size_t)row * 64 + kh * 32 + g * 8, 1.f, axh[mt][kh], axl[mt][kh]);
        #pragma unroll
        for (int j = 0; j < 8; j++) {
            int k = g * 8 + j;
            float v = (k < 6) ? st[(size_t)row * 6 + k] : 0.f;
            unsigned short hb = f2bf(v);
            arh[mt][j] = (short)hb;
            arl[mt][j] = (short)f2bf(v - bf2f(hb));
        }
    }
    #pragma unroll
    for (int nt = 0; nt < 4; nt++) {
        int col = nt * 16 + lm;
        bf16x8 bh[2], blo[2], brh, brl;
        #pragma unroll
        for (int kh = 0; kh < 2; kh++) loadWsplit(Wrel, kh * 32 + g * 8, col, bh[kh], blo[kh]);
        #pragma unroll
        for (int j = 0; j < 8; j++) {
            int k = g * 8 + j;
            float v = (k < 6) ? Wroot[(size_t)k * 64 + col] : 0.f;
            unsigned short hb = f2bf(v);
            brh[j] = (short)hb;
            brl[j] = (short)f2bf(v - bf2f(hb));
        }
        #pragma unroll
        for (int mt = 0; mt < 2; mt++) {
            f32x4 acc = {0.f, 0.f, 0.f, 0.f};
            #pragma unroll
            for (int kh = 0; kh < 2; kh++) {
                acc = __builtin_amdgcn_mfma_f32_16x16x32_bf16(axh[mt][kh], bh[kh],  acc, 0, 0, 0);
                acc = __builtin_amdgcn_mfma_f32_16x16x32_bf16(axl[mt][kh], bh[kh],  acc, 0, 0, 0);
                acc = __builtin_amdgcn_mfma_f32_16x16x32_bf16(axh[mt][kh], blo[kh], acc, 0, 0, 0);
            }
            acc = __builtin_amdgcn_mfma_f32_16x16x32_bf16(arh[mt], brh, acc, 0, 0, 0);
            acc = __builtin_amdgcn_mfma_f32_16x16x32_bf16(arl[mt], brh, acc, 0, 0, 0);
            acc = __builtin_amdgcn_mfma_f32_16x16x32_bf16(arh[mt], brl, acc, 0, 0, 0);
            #pragma unroll
            for (int r = 0; r < 4; r++) {
                int row = r0 + mt * 16 + g * 4 + r;
                if (row < n)
                    out[(size_t)row * 64 + col] = fmaxf(b[col] + acc[r], 0.f);
            }
        }
    }
}

// Fused TAG2 combine + final linear:
// out8 = lin_b + relu(tag2_b + x0@W0 + x1@W1 + x2@W2 + x3@W3) @ lin_W
// Accumulator lives in AGPRs; no fp32 sx3 round-trips, no k_final.
__global__ __launch_bounds__(256)
void k_tagmm(const unsigned short* __restrict__ x0, const unsigned short* __restrict__ x1,
             const unsigned short* __restrict__ x2, const unsigned short* __restrict__ x3,
             const float* __restrict__ W4, const float* __restrict__ tb,
             const float* __restrict__ lW, const float* __restrict__ lb,
             float* __restrict__ out, int n) {
    __shared__ float lds[4][32][64];
    int tid = threadIdx.x;
    int wv = (int)(((long long)blockIdx.x * blockDim.x + tid) >> 6);
    int w = (tid >> 6) & 3;
    int lane = tid & 63;
    int lm = lane & 15, g = lane >> 4;
    int r0 = wv * 32;
    bool active = (r0 < n);
    int r0c = active ? r0 : 0;
    const unsigned short* xs[4] = {x0, x1, x2, x3};
    f32x4 acc[2][4];
    #pragma unroll
    for (int mt = 0; mt < 2; mt++)
        #pragma unroll
        for (int nt = 0; nt < 4; nt++) acc[mt][nt] = (f32x4){0.f, 0.f, 0.f, 0.f};
    #pragma unroll
    for (int inp = 0; inp < 4; inp++) {
        const unsigned short* xp = xs[inp];
        const float* W = W4 + inp * 4096;
        bf16x8 a[2][2];
        #pragma unroll
        for (int mt = 0; mt < 2; mt++) {
            int row = r0c + mt * 16 + lm; if (row >= n) row = n - 1;
            #pragma unroll
            for (int kh = 0; kh < 2; kh++)
                a[mt][kh] = *(const bf16x8*)(xp + (size_t)row * 64 + kh * 32 + g * 8);
        }
        #pragma unroll
        for (int nt = 0; nt < 4; nt++) {
            int col = nt * 16 + lm;
            bf16x8 bh[2], blo[2];
            #pragma unroll
            for (int kh = 0; kh < 2; kh++) loadWsplit(W, kh * 32 + g * 8, col, bh[kh], blo[kh]);
            #pragma unroll
            for (int mt = 0; mt < 2; mt++) {
                #pragma unroll
                for (int kh = 0; kh < 2; kh++) {
                    acc[mt][nt] = __builtin_amdgcn_mfma_f32_16x16x32_bf16(a[mt][kh], bh[kh],  acc[mt][nt], 0, 0, 0);
                    acc[mt][nt] = __builtin_amdgcn_mfma_f32_16x16x32_bf16(a[mt][kh], blo[kh], acc[mt][nt], 0, 0, 0);
                }
            }
        }
    }
    // relu(tb + acc) -> LDS (row-major 32x64 per wave)
    #pragma unroll
    for (int mt = 0; mt < 2; mt++)
        #pragma unroll
        for (int nt = 0; nt < 4; nt++) {
            int col = nt * 16 + lm;
            float bias = tb[col];
            #pragma unroll
            for (int r = 0; r < 4; r++)
                lds[w][mt * 16 + g * 4 + r][col] = fmaxf(bias + acc[mt][nt][r], 0.f);
        }
    __syncthreads();
    // lin: A = relu rows from LDS, B = lin_W (64x8; cols 8..15 zero)
    bf16x8 bh2[2], bl2[2];
    #pragma unroll
    for (int kh = 0; kh < 2; kh++) {
        #pragma unroll
        for (int j = 0; j < 8; j++) {
            int k = kh * 32 + g * 8 + j;
            float v = (lm < 8) ? lW[k * 8 + lm] : 0.f;
            unsigned short hb = f2bf(v);
            bh2[kh][j] = (short)hb;
            bl2[kh][j] = (short)f2bf(v - bf2f(hb));
        }
    }
    #pragma unroll
    for (int mt = 0; mt < 2; mt++) {
        bf16x8 ah[2], al[2];
        #pragma unroll
        for (int kh = 0; kh < 2; kh++) {
            #pragma unroll
            for (int j = 0; j < 8; j++) {
                float v = lds[w][mt * 16 + lm][kh * 32 + g * 8 + j];
                unsigned short hb = f2bf(v);
                ah[kh][j] = (short)hb;
                al[kh][j] = (short)f2bf(v - bf2f(hb));
            }
        }
        f32x4 oacc = {0.f, 0.f, 0.f, 0.f};
        #pragma unroll
        for (int kh = 0; kh < 2; kh++) {
            oacc = __builtin_amdgcn_mfma_f32_16x16x32_bf16(ah[kh], bh2[kh], oacc, 0, 0, 0);
            oacc = __builtin_amdgcn_mfma_f32_16x16x32_bf16(al[kh], bh2[kh], oacc, 0, 0, 0);
            oacc = __builtin_amdgcn_mfma_f32_16x16x32_bf16(ah[kh], bl2[kh], oacc, 0, 0, 0);
        }
        if (lm < 8) {
            #pragma unroll
            for (int r = 0; r < 4; r++) {
                int row = r0 + mt * 16 + g * 4 + r;
                if (active && row < n) out[(size_t)row * 8 + lm] = oacc[r] + lb[lm];
            }
        }
    }
}

// gx_bf = bf16(relu(b + x@W0 + h1@W1 + h2@W2))  (K=5 inputs; VALU is fine)
// h1/h2 are 8-float packets (stride 8)
__global__ __launch_bounds__(256, 4)
void k_tag1_w(const float* __restrict__ x, const float* __restrict__ h1,
              const float* __restrict__ h2, const float* __restrict__ W,
              const float* __restrict__ b, unsigned short* __restrict__ out, int n) {
    int wv = (int)(((long long)blockIdx.x * blockDim.x + threadIdx.x) >> 6);
    int lane = threadIdx.x & 63;
    int i0 = wv * 4;
    if (i0 >= n) return;
    float v[4], acc[4];
    #pragma unroll
    for (int r = 0; r < 4; r++) {
        int i = (i0 + r < n) ? i0 + r : n - 1;
        float t = 0.f;
        if (lane < 5)                     t = x [(size_t)i * 5 + lane];
        else if (lane >= 8 && lane < 13)  t = h1[(size_t)i * 8 + lane - 8];
        else if (lane >= 16 && lane < 21) t = h2[(size_t)i * 8 + lane - 16];
        v[r] = t;
        acc[r] = b[lane];
    }
    #pragma unroll
    for (int m = 0; m < 3; m++) {
        #pragma unroll
        for (int k = 0; k < 5; k++) {
            float wk = W[(m * 5 + k) * 64 + lane];
            #pragma unroll
            for (int r = 0; r < 4; r++) acc[r] += bcast(v[r], m * 8 + k) * wk;
        }
    }
    #pragma unroll
    for (int r = 0; r < 4; r++)
        if (i0 + r < n) out[(size_t)(i0 + r) * 64 + lane] = f2bf(fmaxf(acc[r], 0.f));
}

static inline unsigned gblk(long long n) { return (unsigned)((n + BLK - 1) / BLK); }
static inline unsigned gwv4(long long n) { return gblk(((n + 3) / 4) * 64); }
static inline unsigned gw32(long long n) { return gblk(((n + 31) / 32) * 64); }

extern "C" void kernel_launch(void* const* d_in, const int* in_sizes, int n_in,
                              void* d_out, int out_size, void* d_ws, size_t ws_size,
                              hipStream_t stream) {
    const float* game_x  = (const float*)d_in[0];
    const float* state_x = (const float*)d_in[1];
    const int*   ei_vv   = (const int*)d_in[2];
    const int*   ei_h    = (const int*)d_in[3];
    const float* ea_h    = (const float*)d_in[4];
    const int*   ei_in   = (const int*)d_in[5];
    const int*   ei_ss   = (const int*)d_in[6];
    const float* tag1_W  = (const float*)d_in[7];
    const float* tag1_b  = (const float*)d_in[8];
    const float* tag2_W  = (const float*)d_in[9];
    const float* tag2_b  = (const float*)d_in[10];
    const float* gc_Wrel = (const float*)d_in[11];
    const float* gc_b    = (const float*)d_in[12];
    const float* gc_Wroot= (const float*)d_in[13];
    const float* sage_Wl = (const float*)d_in[14];
    const float* sage_bl = (const float*)d_in[15];
    const float* sage_Wr = (const float*)d_in[16];
    const float* lin_W   = (const float*)d_in[17];
    const float* lin_b   = (const float*)d_in[18];

    const int NV  = in_sizes[0] / 5;
    const int NS  = in_sizes[1] / 6;
    const int EVV = in_sizes[2] / 2;
    const int EH  = in_sizes[3] / 2;
    const int EIN = in_sizes[5] / 2;
    const int ESS = in_sizes[6] / 2;

    const int *vv_s = ei_vv,  *vv_d = ei_vv + EVV;
    const int *h_s  = ei_h,   *h_d  = ei_h  + EH;
    const int *in_s = ei_in,  *in_d = ei_in + EIN;
    const int *ss_s = ei_ss,  *ss_d = ei_ss + ESS;

    // bin geometry
    const int ncv = (EVV + ACH - 1) / ACH;
    const int nch = (EH  + ACH - 1) / ACH;
    const int nci = (EIN + ACH - 1) / ACH;
    const int ncs = (ESS + ACH - 1) / ACH;
    const int nbv_ = (NV + 255) >> 8;
    const int nbs_ = (NS + 127) >> 7;
    const int Lv = nbv_ * ncv, Lh = nbs_ * nch, Li = nbs_ * nci, Ls = nbs_ * ncs;
    const int nB0 = (Lv + 255) / 256, nB1 = (Lh + 255) / 256,
              nB2 = (Li + 255) / 256, nB3 = (Ls + 255) / 256;

    // ---------------- workspace layout (4-byte words) ----------------
    float* wsf = (float*)d_ws;
    size_t o = 0;
    unsigned short* gx_bf = (unsigned short*)(wsf + o);   // NV x 64 bf16
    o += (size_t)NV * 32;
    float* B1 = wsf + o; o += (size_t)NS * 64;            // binned vv|in|ss | agg | ssum | hA_bf
    float* B2 = wsf + o; o += (size_t)NS * 64;            // binned h | sx | hB_bf
    float* B4 = wsf + o; o += (size_t)NS * 32;            // H1+H2 packets (NV*16) | sx2_bf (NS*32)
    float* B5 = wsf + o; o += (size_t)NS * 32;            // P0 packets (NV*8) | hC_bf (NS*32)
    int*  vvsrc = (int*)(wsf + o); o += (size_t)EVV;
    int*  sssrc = (int*)(wsf + o); o += (size_t)ESS;
    int*  insrc = (int*)(wsf + o); o += (size_t)EIN;
    int2* hsw   = (int2*)(wsf + o); o += (size_t)EH * 2;
    int* T_all = (int*)(wsf + o); o += (size_t)(Lv + Lh + Li + Ls);
    int* bsum  = (int*)(wsf + o); o += 2048;
    int* rv = (int*)(wsf + o); o += (size_t)NV + 1;
    int* rh = (int*)(wsf + o); o += (size_t)NS + 1;
    int* ri = (int*)(wsf + o); o += (size_t)NS + 1;
    int* rs = (int*)(wsf + o); o += (size_t)NS + 1;
    float* dinv_v = wsf + o; o += (size_t)NV;
    float* dinv_s = wsf + o; o += (size_t)NS;

    int* Tv = T_all;
    int* Th = Tv + Lv;
    int* Ti = Th + Lh;
    int* Ts = Ti + Li;

    // phase-0 binned edge buffers alias B1/B2 (dead until stage B)
    unsigned* vvbin = (unsigned*)B1;
    unsigned* inbin = vvbin + EVV;
    unsigned* ssbin = inbin + EIN;
    int2* hbin = (int2*)B2;

    unsigned short* hA_bf  = (unsigned short*)B1;
    unsigned short* hB_bf  = (unsigned short*)B2;
    unsigned short* hC_bf  = (unsigned short*)B5;
    unsigned short* sx2_bf = (unsigned short*)B4;
    float* P0 = B5;                         // packed (x,dinv) NV*8 floats
    float* H1 = B4;                         // packed hop-1     NV*8 floats
    float* H2 = B4 + (size_t)NV * 8;        // packed hop-2     NV*8 floats

    // ================= Phase 0: atomic-free batched CSR build =================
    int nbins   = nbv_ + 3 * nbs_;
    int nBtot   = nB0 + nB1 + nB2 + nB3;
    k_binA1<<<ncv + nch + nci + ncs, 256, 0, stream>>>(vv_d, h_d, in_d, ss_d, Tv, Th, Ti, Ts,
                                         ncv, nch, nci, ncs, nbv_, nbs_,
                                         EVV, EH, EIN, ESS);
    k_sb2<<<nBtot, 256, 0, stream>>>(T_all, bsum, Lv, Lh, Li, Ls, nB0, nB1, nB2, nB3);
    k_st2<<<4, 1024, 0, stream>>>(bsum, nB0, nB1, nB2, nB3);
    k_sa2<<<nBtot, 256, 0, stream>>>(T_all, bsum, Lv, Lh, Li, Ls, nB0, nB1, nB2, nB3);
    k_binA2a<<<ncv + nci + ncs, 512, 0, stream>>>(vv_s, vv_d, in_s, in_d, ss_s, ss_d,
                                                  Tv, Ti, Ts, vvbin, inbin, ssbin,
                                                  ncv, nci, ncs, nbv_, nbs_,
                                                  EVV, EIN, ESS);
    k_binA2h<<<nch, 512, 0, stream>>>(h_s, h_d, ea_h, Th, hbin, nch, nbs_, EH);
    k_binB<<<nbins, 256, 0, stream>>>(vvbin, hbin, inbin, ssbin,
                                      Tv, Th, Ti, Ts,
                                      rv, rh, ri, rs, dinv_v, dinv_s,
                                      vvsrc, hsw, insrc, sssrc,
                                      ncv, nch, nci, ncs, nbv_, nbs_,
                                      NV, NS, EVV, EH, EIN, ESS);

    // ================= Stage A: TAGConv1 on v-v (packet form) =================
    k_pack5<<<gblk(NV), BLK, 0, stream>>>(game_x, dinv_v, P0, NV);
    k_gather5p<<<gblk(NV), BLK, 0, stream>>>(P0, rv, vvsrc, H1, NV);
    k_gather5p<<<gblk(NV), BLK, 0, stream>>>(H1, rv, vvsrc, H2, NV);
    k_tag1_w<<<gwv4(NV), BLK, 0, stream>>>(game_x, H1, H2, tag1_W, tag1_b, gx_bf, NV);

    // ================= Stage B: GraphConv (weighted) =================
    k_gather64<1, false><<<gblk((long long)NS * 64), BLK, 0, stream>>>(gx_bf, rh, nullptr, hsw, nullptr, B1, NS);
    k_gc_mf<<<gw32(NS), BLK, 0, stream>>>(B1, state_x, gc_Wrel, gc_Wroot, gc_b, B2, NS);

    // ================= Stage C: SAGE mean =================
    k_gather64<0, false><<<gblk((long long)NS * 64), BLK, 0, stream>>>(gx_bf, ri, insrc, nullptr, nullptr, B1, NS);
    k_sage_mf<<<gw32(NS), BLK, 0, stream>>>(B1, ri, B2, sage_Wl, sage_Wr, sage_bl, sx2_bf, NS);

    // ================= Stage D: TAGConv2 hops (gathers only), then fused dense
    k_gather64<2, true><<<gblk((long long)NS * 64), BLK, 0, stream>>>(sx2_bf, rs, sssrc, nullptr, dinv_s, hA_bf, NS);
    k_gather64<2, true><<<gblk((long long)NS * 64), BLK, 0, stream>>>(hA_bf, rs, sssrc, nullptr, dinv_s, hB_bf, NS);
    k_gather64<2, true><<<gblk((long long)NS * 64), BLK, 0, stream>>>(hB_bf, rs, sssrc, nullptr, dinv_s, hC_bf, NS);
    k_tagmm<<<gw32(NS), BLK, 0, stream>>>(sx2_bf, hA_bf, hB_bf, hC_bf,
                                          tag2_W, tag2_b, lin_W, lin_b,
                                          (float*)d_out, NS);
}